// Round 1
// baseline (1516.772 us; speedup 1.0000x reference)
//
#include <hip/hip_runtime.h>
#include <math.h>

// Cyborg stack machine: B=256, S=128, V=512, H=30, N_STACKS=2, R=2, DEPTH=4
// Strategy: all stack/peek/output vectors live in span{ones, init_vec, syms0..29}
// (32-dim). Recurrence runs in coordinate space; only the x-side NAND dots need
// full 512-dim GEMM (precomputed).

#define SS 128
#define VV 512
#define NROWS 208      // 8 pop + 8 pushop + 128 pushfn + 64 calc
#define ZOFF 1e-6f

// ws layout (float offsets)
#define OFF_I0   0                          // interp0: 32768*208
#define OFF_OC   (32768*208)                // out coords: 32768*32
#define OFF_G    (OFF_OC + 32768*32)        // G[2][32][208]
#define OFF_M    (OFF_G + 2*32*208)         // Gram 32*32
#define OFF_A    (OFF_M + 1024)             // A coef 208*3
#define OFF_Bc   (OFF_A + 624)              // B coef 208*3
#define OFF_W0   (OFF_Bc + 624)             // gathered w j=0 slice 208*512

__device__ __forceinline__ const float* w_row(int r, const float* pw, const float* pow_,
                                              const float* pfw, const float* cw) {
    if (r < 8)   return pw   + r * 1536;
    if (r < 16)  return pow_ + (r - 8) * 1536;
    if (r < 144) return pfw  + (r - 16) * 1536;
    return cw + (r - 144) * 1536;
}
__device__ __forceinline__ const float* nw_row(int r, const float* pn, const float* pon,
                                               const float* pfn, const float* cn) {
    if (r < 8)   return pn   + r * 3;
    if (r < 16)  return pon  + (r - 8) * 3;
    if (r < 144) return pfn  + (r - 16) * 3;
    return cn + (r - 144) * 3;
}

// ---------------- kernel B: precompute tables ----------------
__global__ void kB(const float* __restrict__ syms, const float* __restrict__ siv,
                   const float* __restrict__ pw, const float* __restrict__ pn,
                   const float* __restrict__ pow_, const float* __restrict__ pon,
                   const float* __restrict__ pfw, const float* __restrict__ pfn,
                   const float* __restrict__ cw, const float* __restrict__ cn,
                   float* __restrict__ ws) {
    int blk = blockIdx.x, tid = threadIdx.x;
    if (blk < 64) {
        // G[jj][m][c] = basis_m . w_row(c)[(jj+1)*512 .. +512)
        int jj = blk >> 5, m = blk & 31;
        __shared__ float bas[512];
        for (int i = tid; i < 512; i += 256)
            bas[i] = (m == 0) ? 1.0f : ((m == 1) ? siv[i] : syms[(m - 2) * 512 + i]);
        __syncthreads();
        if (tid < NROWS) {
            const float4* w4 = (const float4*)(w_row(tid, pw, pow_, pfw, cw) + (jj + 1) * 512);
            const float4* b4 = (const float4*)bas;
            float s = 0.f;
            for (int q = 0; q < 128; ++q) {
                float4 a = b4[q], b = w4[q];
                s += a.x * b.x + a.y * b.y + a.z * b.z + a.w * b.w;
            }
            ws[OFF_G + (jj * 32 + m) * 208 + tid] = s;
        }
    } else if (blk == 64) {
        // Gram M[m][mm]
        __shared__ float basw[32 * 512];
        for (int i = tid; i < 32 * 512; i += 256) {
            int m = i >> 9, v = i & 511;
            basw[i] = (m == 0) ? 1.0f : ((m == 1) ? siv[v] : syms[(m - 2) * 512 + v]);
        }
        __syncthreads();
        for (int p = tid; p < 1024; p += 256) {
            int m = p >> 5, mm = p & 31;
            const float4* a4 = (const float4*)(basw + m * 512);
            const float4* b4 = (const float4*)(basw + mm * 512);
            float s = 0.f;
            for (int q = 0; q < 128; ++q) {
                float4 a = a4[q], b = b4[q];
                s += a.x * b.x + a.y * b.y + a.z * b.z + a.w * b.w;
            }
            ws[OFF_M + p] = s;
        }
    } else if (blk == 65) {
        // folded NAND coefs: A=(2*sig-1)/||w||, B=1-sig   for (r, j)
        for (int idx = tid; idx < 624; idx += 256) {
            int r = idx / 3, j = idx % 3;
            const float4* w4 = (const float4*)(w_row(r, pw, pow_, pfw, cw) + j * 512);
            float s = 0.f;
            for (int q = 0; q < 128; ++q) {
                float4 b = w4[q];
                s += b.x * b.x + b.y * b.y + b.z * b.z + b.w * b.w;
            }
            float nrm = fmaxf(sqrtf(s), 1e-8f);
            float nwv = nw_row(r, pn, pon, pfn, cn)[j];
            float sig = 1.f / (1.f + expf(-nwv));
            ws[OFF_A + idx]  = (2.f * sig - 1.f) / nrm;
            ws[OFF_Bc + idx] = 1.f - sig;
        }
    } else {
        // gather w j=0 slice into contiguous [208][512]
        int half = blk - 66;
        for (int i = tid; i < 53248; i += 256) {
            int flat = half * 53248 + i;
            int c = flat >> 9, v = flat & 511;
            ws[OFF_W0 + flat] = w_row(c, pw, pow_, pfw, cw)[v];
        }
    }
}

// ---------------- kernel A: interp0 (x-side NAND term) ----------------
// interp0[bt][c] = A0[c]*|x_bt . w0[c]|*invnorm(x_bt) + B0[c]
__global__ __launch_bounds__(256) void kA(const float* __restrict__ x, float* __restrict__ ws) {
    __shared__ float xs[32 * 512];
    __shared__ float red[32][8];
    __shared__ float invx[32];
    int blk = blockIdx.x, tid = threadIdx.x;
    const float4* x4 = (const float4*)x;
    float4* xs4 = (float4*)xs;
    for (int i = 0; i < 16; ++i)
        xs4[i * 256 + tid] = x4[(size_t)blk * 4096 + i * 256 + tid];
    __syncthreads();
    {
        int r = tid >> 3, seg = tid & 7;
        const float4* xr = (const float4*)(xs + r * 512) + seg * 16;
        float s = 0.f;
        for (int q = 0; q < 16; ++q) { float4 a = xr[q]; s += a.x*a.x + a.y*a.y + a.z*a.z + a.w*a.w; }
        red[r][seg] = s;
    }
    __syncthreads();
    if (tid < 32) {
        float s = 0.f;
        for (int q = 0; q < 8; ++q) s += red[tid][q];
        invx[tid] = 1.f / fmaxf(sqrtf(s), 1e-8f);
    }
    __syncthreads();
    int tx = tid & 15, ty = tid >> 4;
    int r0 = ty * 2, r1 = r0 + 1;
    float acc0[13], acc1[13], a0[13], b0[13];
    for (int j = 0; j < 13; ++j) {
        int c = tx + 16 * j;
        acc0[j] = 0.f; acc1[j] = 0.f;
        a0[j] = ws[OFF_A + c * 3];
        b0[j] = ws[OFF_Bc + c * 3];
    }
    const float4* w4 = (const float4*)(ws + OFF_W0);
    const float4* xr0 = (const float4*)(xs + r0 * 512);
    const float4* xr1 = (const float4*)(xs + r1 * 512);
    for (int q = 0; q < 128; ++q) {
        float4 xa = xr0[q], xb = xr1[q];
        for (int j = 0; j < 13; ++j) {
            int c = tx + 16 * j;
            float4 wv = w4[c * 128 + q];
            acc0[j] += xa.x * wv.x + xa.y * wv.y + xa.z * wv.z + xa.w * wv.w;
            acc1[j] += xb.x * wv.x + xb.y * wv.y + xb.z * wv.z + xb.w * wv.w;
        }
    }
    float ix0 = invx[r0], ix1 = invx[r1];
    int bt = blk * 32;
    for (int j = 0; j < 13; ++j) {
        int c = tx + 16 * j;
        ws[OFF_I0 + (size_t)(bt + r0) * 208 + c] = a0[j] * fabsf(acc0[j]) * ix0 + b0[j];
        ws[OFF_I0 + (size_t)(bt + r1) * 208 + c] = a0[j] * fabsf(acc1[j]) * ix1 + b0[j];
    }
}

// ---------------- kernel C: sequential recurrence in coord space ----------------
__global__ __launch_bounds__(256) void kC(float* __restrict__ ws, const float* __restrict__ sharp) {
    __shared__ float sG[2 * 32 * 208];
    __shared__ float sM[32 * 33];
    __shared__ float sA[208 * 2], sB[208 * 2];
    __shared__ float st[2 * 4 * 32];
    __shared__ float sptr[2 * 4];
    __shared__ float pk[2 * 32];
    __shared__ float tmpv[2 * 32];
    __shared__ float invq[2];
    __shared__ float i0[208];
    __shared__ float nnd[208];
    __shared__ float pvs[2 * 32];
    __shared__ float gate[2][4];
    __shared__ float pvc[2 * 32];
    __shared__ float ssh[2];
    int b = blockIdx.x, tid = threadIdx.x;
    for (int i = tid; i < 13312; i += 256) sG[i] = ws[OFF_G + i];
    for (int i = tid; i < 1024; i += 256) sM[(i >> 5) * 33 + (i & 31)] = ws[OFF_M + i];
    if (tid < 208) {
        sA[tid * 2]     = ws[OFF_A + tid * 3 + 1];
        sA[tid * 2 + 1] = ws[OFF_A + tid * 3 + 2];
        sB[tid * 2]     = ws[OFF_Bc + tid * 3 + 1];
        sB[tid * 2 + 1] = ws[OFF_Bc + tid * 3 + 2];
    }
    {   // init: slot1 = init_vec (coord m=1), others = ZOFF*ones (coord m=0); ptr at slot 1
        int k = tid >> 7, d = (tid >> 5) & 3, m = tid & 31;
        st[(k * 4 + d) * 32 + m] = (d == 1) ? ((m == 1) ? 1.f : 0.f) : ((m == 0) ? ZOFF : 0.f);
        if (m == 0) sptr[k * 4 + d] = (d == 1) ? 1.f : 0.f;
    }
    if (tid < 2) ssh[tid] = sharp[tid];
    __syncthreads();

    for (int t = 0; t < SS; ++t) {
        size_t bt = (size_t)b * SS + t;
        if (tid < 208) i0[tid] = ws[OFF_I0 + bt * 208 + tid];
        if (tid < 64) {             // peek coords
            int k = tid >> 5, m = tid & 31;
            float s = 0.f;
            for (int d = 0; d < 4; ++d) s += st[(k * 4 + d) * 32 + m] * sptr[k * 4 + d];
            pk[tid] = s;
        }
        __syncthreads();
        if (tid < 64) {             // Gram matvec for norms
            int k = tid >> 5, m = tid & 31;
            float s = 0.f;
            for (int mm = 0; mm < 32; ++mm) s += sM[m * 33 + mm] * pk[k * 32 + mm];
            tmpv[tid] = s * pk[tid];
        }
        __syncthreads();
        if (tid < 2) {
            float s = 0.f;
            for (int m = 0; m < 32; ++m) s += tmpv[tid * 32 + m];
            invq[tid] = 1.f / fmaxf(sqrtf(s), 1e-8f);
        }
        __syncthreads();
        if (tid < 144) {            // phase-1 NAND rows
            float d1 = 0.f, d2 = 0.f;
            for (int m = 0; m < 32; ++m) {
                d1 += pk[m]      * sG[m * 208 + tid];
                d2 += pk[32 + m] * sG[(32 + m) * 208 + tid];
            }
            float i1 = sA[tid * 2]     * fabsf(d1) * invq[0] + sB[tid * 2];
            float i2 = sA[tid * 2 + 1] * fabsf(d2) * invq[1] + sB[tid * 2 + 1];
            nnd[tid] = i0[tid] * i1 * i2;
        }
        __syncthreads();
        if (tid < 4) {              // pop / push gates
            int k = tid >> 1, which = tid & 1;
            int base = (which ? 8 : 0) + 4 * k;
            float sp = fmaxf(nnd[base], nnd[base + 1]);
            float sn = fmaxf(nnd[base + 2], nnd[base + 3]);
            float sh = ssh[k];
            float e0 = expf(sp * sh), e1 = expf(sn * sh);
            float p0 = e0 / (e0 + e1);
            gate[k][which * 2] = p0; gate[k][which * 2 + 1] = 1.f - p0;
        }
        if (tid >= 64 && tid < 128) {  // push_fn pair sums
            int idx = tid - 64; int k = idx >> 5, o = idx & 31;
            pvs[idx] = nnd[16 + 64 * k + 2 * o] + nnd[16 + 64 * k + 2 * o + 1];
        }
        __syncthreads();
        if (tid < 64) {             // push_val coords (old peeks)
            int k = tid >> 5, m = tid & 31;
            float v = pvs[k * 32 + 30] * pk[m] + pvs[k * 32 + 31] * pk[32 + m];
            if (m >= 2) v += pvs[k * 32 + m - 2];
            pvc[tid] = v;
        }
        __syncthreads();
        {                           // stack update: pop_or_nop then push_or_nop
            int k = tid >> 7, d = (tid >> 5) & 3, m = tid & 31;
            float prp0 = gate[k][0], prp1 = gate[k][1];
            float prq0 = gate[k][2], prq1 = gate[k][3];
            float pd   = sptr[k * 4 + d];
            float pdp1 = sptr[k * 4 + ((d + 1) & 3)];
            float pdm1 = sptr[k * 4 + ((d + 3) & 3)];
            float sold = st[(k * 4 + d) * 32 + m];
            float ps = sold * (1.f - pd) + ((m == 0) ? ZOFF : 0.f) * pd;
            float s1 = ps * prp0 + sold * prp1;
            float p1_d   = pdp1 * prp0 + pd * prp1;
            float p1_dm1 = pd * prp0 + pdm1 * prp1;   // p1 at slot d-1
            float pu = p1_dm1;                         // roll(+1) at slot d
            float su = s1 * (1.f - pu) + pvc[k * 32 + m] * pu;
            float s2 = su * prq0 + s1 * prq1;
            float p2 = pu * prq0 + p1_d * prq1;
            __syncthreads();
            st[(k * 4 + d) * 32 + m] = s2;
            if (m == 0) sptr[k * 4 + d] = p2;
        }
        __syncthreads();
        // ---- phase 2 ----
        if (tid < 64) {
            int k = tid >> 5, m = tid & 31;
            float s = 0.f;
            for (int d = 0; d < 4; ++d) s += st[(k * 4 + d) * 32 + m] * sptr[k * 4 + d];
            pk[tid] = s;
        }
        __syncthreads();
        if (tid < 64) {
            int k = tid >> 5, m = tid & 31;
            float s = 0.f;
            for (int mm = 0; mm < 32; ++mm) s += sM[m * 33 + mm] * pk[k * 32 + mm];
            tmpv[tid] = s * pk[tid];
        }
        __syncthreads();
        if (tid < 2) {
            float s = 0.f;
            for (int m = 0; m < 32; ++m) s += tmpv[tid * 32 + m];
            invq[tid] = 1.f / fmaxf(sqrtf(s), 1e-8f);
        }
        __syncthreads();
        if (tid < 64) {             // calc rows
            int c = 144 + tid;
            float d1 = 0.f, d2 = 0.f;
            for (int m = 0; m < 32; ++m) {
                d1 += pk[m]      * sG[m * 208 + c];
                d2 += pk[32 + m] * sG[(32 + m) * 208 + c];
            }
            float i1 = sA[c * 2]     * fabsf(d1) * invq[0] + sB[c * 2];
            float i2 = sA[c * 2 + 1] * fabsf(d2) * invq[1] + sB[c * 2 + 1];
            nnd[c] = i0[c] * i1 * i2;
        }
        __syncthreads();
        if (tid < 32) pvs[tid] = nnd[144 + 2 * tid] + nnd[144 + 2 * tid + 1];
        __syncthreads();
        if (tid < 32) {             // output coords
            int m = tid;
            float v = pvs[30] * pk[m] + pvs[31] * pk[32 + m];
            if (m >= 2) v += pvs[m - 2];
            ws[OFF_OC + bt * 32 + m] = v;
        }
        __syncthreads();
    }
}

// ---------------- kernel D: expand coords -> 512-dim output ----------------
__global__ __launch_bounds__(256) void kD(const float* __restrict__ ws, const float* __restrict__ syms,
                                          const float* __restrict__ siv, float* __restrict__ out) {
    __shared__ float bas[31 * 512];   // m=0: siv, m=1..30: syms
    __shared__ float ocr[32];
    int blk = blockIdx.x, tid = threadIdx.x;
    for (int i = tid; i < 31 * 512; i += 256) {
        int m = i >> 9, v = i & 511;
        bas[i] = (m == 0) ? siv[v] : syms[(m - 1) * 512 + v];
    }
    __syncthreads();
    for (int r = 0; r < 128; ++r) {
        size_t bt = (size_t)blk * 128 + r;
        if (tid < 32) ocr[tid] = ws[OFF_OC + bt * 32 + tid];
        __syncthreads();
        int v = tid * 2;
        float s0 = ocr[0], s1 = ocr[0];   // ones-basis contribution
        for (int m = 0; m < 31; ++m) {
            float c = ocr[m + 1];
            s0 += c * bas[m * 512 + v];
            s1 += c * bas[m * 512 + v + 1];
        }
        ((float2*)out)[bt * 256 + tid] = make_float2(s0, s1);
        __syncthreads();
    }
}

extern "C" void kernel_launch(void* const* d_in, const int* in_sizes, int n_in,
                              void* d_out, int out_size, void* d_ws, size_t ws_size,
                              hipStream_t stream) {
    const float* x    = (const float*)d_in[0];
    const float* syms = (const float*)d_in[1];
    const float* siv  = (const float*)d_in[2];
    const float* shp  = (const float*)d_in[3];
    const float* pw   = (const float*)d_in[4];
    const float* pn   = (const float*)d_in[5];
    const float* pow_ = (const float*)d_in[6];
    const float* pon  = (const float*)d_in[7];
    const float* pfw  = (const float*)d_in[8];
    const float* pfn  = (const float*)d_in[9];
    const float* cw   = (const float*)d_in[10];
    const float* cn   = (const float*)d_in[11];
    float* ws  = (float*)d_ws;
    float* out = (float*)d_out;

    hipLaunchKernelGGL(kB, dim3(68),   dim3(256), 0, stream,
                       syms, siv, pw, pn, pow_, pon, pfw, pfn, cw, cn, ws);
    hipLaunchKernelGGL(kA, dim3(1024), dim3(256), 0, stream, x, ws);
    hipLaunchKernelGGL(kC, dim3(256),  dim3(256), 0, stream, ws, shp);
    hipLaunchKernelGGL(kD, dim3(256),  dim3(256), 0, stream, ws, syms, siv, out);
}

// Round 2
// 893.397 us; speedup vs baseline: 1.6978x; 1.6978x over previous
//
#include <hip/hip_runtime.h>
#include <math.h>

// Cyborg stack machine: B=256, S=128, V=512, H=30, N_STACKS=2, R=2, DEPTH=4
// Strategy: all stack/peek/output vectors live in span{ones, init_vec, syms0..29}
// (32-dim). Recurrence runs in coordinate space; only the x-side NAND dots need
// full 512-dim GEMM (kA, LDS-tiled f32 GEMM).

#define SS 128
#define VV 512
#define NROWS 208      // 8 pop + 8 pushop + 128 pushfn + 64 calc
#define ZOFF 1e-6f

// ws layout (float offsets)
#define OFF_I0   0                          // interp0: 32768*208
#define OFF_OC   (32768*208)                // out coords: 32768*32
#define OFF_G    (OFF_OC + 32768*32)        // G[2][32][208]
#define OFF_M    (OFF_G + 2*32*208)         // Gram 32*32
#define OFF_A    (OFF_M + 1024)             // A coef 208*3
#define OFF_Bc   (OFF_A + 624)              // B coef 208*3
#define OFF_W0   (OFF_Bc + 624)             // gathered w j=0 slice [208][512]

__device__ __forceinline__ const float* w_row(int r, const float* pw, const float* pow_,
                                              const float* pfw, const float* cw) {
    if (r < 8)   return pw   + r * 1536;
    if (r < 16)  return pow_ + (r - 8) * 1536;
    if (r < 144) return pfw  + (r - 16) * 1536;
    return cw + (r - 144) * 1536;
}
__device__ __forceinline__ const float* nw_row(int r, const float* pn, const float* pon,
                                               const float* pfn, const float* cn) {
    if (r < 8)   return pn   + r * 3;
    if (r < 16)  return pon  + (r - 8) * 3;
    if (r < 144) return pfn  + (r - 16) * 3;
    return cn + (r - 144) * 3;
}

// ---------------- kernel B: precompute tables ----------------
__global__ void kB(const float* __restrict__ syms, const float* __restrict__ siv,
                   const float* __restrict__ pw, const float* __restrict__ pn,
                   const float* __restrict__ pow_, const float* __restrict__ pon,
                   const float* __restrict__ pfw, const float* __restrict__ pfn,
                   const float* __restrict__ cw, const float* __restrict__ cn,
                   float* __restrict__ ws) {
    int blk = blockIdx.x, tid = threadIdx.x;
    if (blk < 64) {
        // G[jj][m][c] = basis_m . w_row(c)[(jj+1)*512 .. +512)
        int jj = blk >> 5, m = blk & 31;
        __shared__ float bas[512];
        for (int i = tid; i < 512; i += 256)
            bas[i] = (m == 0) ? 1.0f : ((m == 1) ? siv[i] : syms[(m - 2) * 512 + i]);
        __syncthreads();
        if (tid < NROWS) {
            const float4* w4 = (const float4*)(w_row(tid, pw, pow_, pfw, cw) + (jj + 1) * 512);
            const float4* b4 = (const float4*)bas;
            float s = 0.f;
            for (int q = 0; q < 128; ++q) {
                float4 a = b4[q], b = w4[q];
                s += a.x * b.x + a.y * b.y + a.z * b.z + a.w * b.w;
            }
            ws[OFF_G + (jj * 32 + m) * 208 + tid] = s;
        }
    } else if (blk == 64) {
        // Gram M[m][mm]
        __shared__ float basw[32 * 512];
        for (int i = tid; i < 32 * 512; i += 256) {
            int m = i >> 9, v = i & 511;
            basw[i] = (m == 0) ? 1.0f : ((m == 1) ? siv[v] : syms[(m - 2) * 512 + v]);
        }
        __syncthreads();
        for (int p = tid; p < 1024; p += 256) {
            int m = p >> 5, mm = p & 31;
            const float4* a4 = (const float4*)(basw + m * 512);
            const float4* b4 = (const float4*)(basw + mm * 512);
            float s = 0.f;
            for (int q = 0; q < 128; ++q) {
                float4 a = a4[q], b = b4[q];
                s += a.x * b.x + a.y * b.y + a.z * b.z + a.w * b.w;
            }
            ws[OFF_M + p] = s;
        }
    } else if (blk == 65) {
        // folded NAND coefs: A=(2*sig-1)/||w||, B=1-sig   for (r, j)
        for (int idx = tid; idx < 624; idx += 256) {
            int r = idx / 3, j = idx % 3;
            const float4* w4 = (const float4*)(w_row(r, pw, pow_, pfw, cw) + j * 512);
            float s = 0.f;
            for (int q = 0; q < 128; ++q) {
                float4 b = w4[q];
                s += b.x * b.x + b.y * b.y + b.z * b.z + b.w * b.w;
            }
            float nrm = fmaxf(sqrtf(s), 1e-8f);
            float nwv = nw_row(r, pn, pon, pfn, cn)[j];
            float sig = 1.f / (1.f + expf(-nwv));
            ws[OFF_A + idx]  = (2.f * sig - 1.f) / nrm;
            ws[OFF_Bc + idx] = 1.f - sig;
        }
    } else {
        // gather w j=0 slice into contiguous [208][512]
        int half = blk - 66;
        for (int i = tid; i < 53248; i += 256) {
            int flat = half * 53248 + i;
            int c = flat >> 9, v = flat & 511;
            ws[OFF_W0 + flat] = w_row(c, pw, pow_, pfw, cw)[v];
        }
    }
}

// ---------------- kernel A: interp0 via LDS-tiled f32 GEMM ----------------
// interp0[bt][c] = A0[c]*|x_bt . w0[c]|*invnorm(x_bt) + B0[c]
// M=32768 (64/block), N=208, K=512 (tiles of 32). Thread tile 4 rows x 13 cols.
__global__ __launch_bounds__(256) void kA(const float* __restrict__ x, float* __restrict__ ws) {
    __shared__ float xs[64 * 36];     // x tile, pad to 36 for float4-aligned, conflict-light reads
    __shared__ float wsh[208 * 36];   // w tile
    __shared__ float red[256];
    __shared__ float invx[64];
    int blk = blockIdx.x, tid = threadIdx.x;
    size_t bt0 = (size_t)blk * 64;

    // row inverse norms (coalesced float4 pass over this block's 64 x-rows)
    {
        int r = tid >> 2, seg = tid & 3;
        const float4* xr = (const float4*)(x + (bt0 + r) * 512 + seg * 128);
        float s = 0.f;
        for (int q = 0; q < 32; ++q) {
            float4 a = xr[q];
            s += a.x * a.x + a.y * a.y + a.z * a.z + a.w * a.w;
        }
        red[tid] = s;
    }
    __syncthreads();
    if (tid < 64) {
        float s = red[tid * 4] + red[tid * 4 + 1] + red[tid * 4 + 2] + red[tid * 4 + 3];
        invx[tid] = 1.f / fmaxf(sqrtf(s), 1e-8f);
    }

    int tx = tid & 15, ty = tid >> 4;   // tx -> 13 cols (c = tx+16j), ty -> 4 rows
    float acc[4][13];
    for (int rr = 0; rr < 4; ++rr)
        for (int j = 0; j < 13; ++j) acc[rr][j] = 0.f;

    const float* w0 = ws + OFF_W0;
    for (int kt = 0; kt < 16; ++kt) {
        __syncthreads();
        // stage x tile: 64 rows x 32 k (coalesced: consecutive lanes -> consecutive k)
        for (int it = 0; it < 8; ++it) {
            int i = tid + 256 * it;
            int r = i >> 5, kk = i & 31;
            xs[r * 36 + kk] = x[(bt0 + r) * 512 + kt * 32 + kk];
        }
        // stage w tile: 208 rows x 32 k
        for (int i = tid; i < 6656; i += 256) {
            int c = i >> 5, kk = i & 31;
            wsh[c * 36 + kk] = w0[c * 512 + kt * 32 + kk];
        }
        __syncthreads();
        for (int g = 0; g < 8; ++g) {
            int k = g * 4;
            float4 a4[4], b4[13];
            for (int rr = 0; rr < 4; ++rr)
                a4[rr] = *(const float4*)(xs + (ty * 4 + rr) * 36 + k);
            for (int j = 0; j < 13; ++j)
                b4[j] = *(const float4*)(wsh + (tx + 16 * j) * 36 + k);
            for (int rr = 0; rr < 4; ++rr)
                for (int j = 0; j < 13; ++j) {
                    float4 a = a4[rr], b = b4[j];
                    acc[rr][j] += a.x * b.x + a.y * b.y + a.z * b.z + a.w * b.w;
                }
        }
    }
    // epilogue: fold NAND affine + row norm, write interp0
    for (int rr = 0; rr < 4; ++rr) {
        int r = ty * 4 + rr;
        float ix = invx[r];
        size_t row = (bt0 + r) * 208;
        for (int j = 0; j < 13; ++j) {
            int c = tx + 16 * j;
            float A0 = ws[OFF_A + c * 3];
            float B0 = ws[OFF_Bc + c * 3];
            ws[OFF_I0 + row + c] = A0 * fabsf(acc[rr][j]) * ix + B0;
        }
    }
}

// ---------------- kernel C: sequential recurrence in coord space ----------------
__global__ __launch_bounds__(256) void kC(float* __restrict__ ws, const float* __restrict__ sharp) {
    __shared__ float sG[2 * 32 * 208];
    __shared__ float sM[32 * 33];
    __shared__ float sA[208 * 2], sB[208 * 2];
    __shared__ float st[2 * 4 * 32];
    __shared__ float sptr[2 * 4];
    __shared__ float pk[2 * 32];
    __shared__ float tmpv[2 * 32];
    __shared__ float invq[2];
    __shared__ float i0[208];
    __shared__ float nnd[208];
    __shared__ float pvs[2 * 32];
    __shared__ float gate[2][4];
    __shared__ float pvc[2 * 32];
    __shared__ float ssh[2];
    int b = blockIdx.x, tid = threadIdx.x;
    for (int i = tid; i < 13312; i += 256) sG[i] = ws[OFF_G + i];
    for (int i = tid; i < 1024; i += 256) sM[(i >> 5) * 33 + (i & 31)] = ws[OFF_M + i];
    if (tid < 208) {
        sA[tid * 2]     = ws[OFF_A + tid * 3 + 1];
        sA[tid * 2 + 1] = ws[OFF_A + tid * 3 + 2];
        sB[tid * 2]     = ws[OFF_Bc + tid * 3 + 1];
        sB[tid * 2 + 1] = ws[OFF_Bc + tid * 3 + 2];
    }
    {   // init: slot1 = init_vec (coord m=1), others = ZOFF*ones (coord m=0); ptr at slot 1
        int k = tid >> 7, d = (tid >> 5) & 3, m = tid & 31;
        st[(k * 4 + d) * 32 + m] = (d == 1) ? ((m == 1) ? 1.f : 0.f) : ((m == 0) ? ZOFF : 0.f);
        if (m == 0) sptr[k * 4 + d] = (d == 1) ? 1.f : 0.f;
    }
    if (tid < 2) ssh[tid] = sharp[tid];
    __syncthreads();

    for (int t = 0; t < SS; ++t) {
        size_t bt = (size_t)b * SS + t;
        if (tid < 208) i0[tid] = ws[OFF_I0 + bt * 208 + tid];
        if (tid < 64) {             // peek coords
            int k = tid >> 5, m = tid & 31;
            float s = 0.f;
            for (int d = 0; d < 4; ++d) s += st[(k * 4 + d) * 32 + m] * sptr[k * 4 + d];
            pk[tid] = s;
        }
        __syncthreads();
        if (tid < 64) {             // Gram matvec for norms
            int k = tid >> 5, m = tid & 31;
            float s = 0.f;
            for (int mm = 0; mm < 32; ++mm) s += sM[m * 33 + mm] * pk[k * 32 + mm];
            tmpv[tid] = s * pk[tid];
        }
        __syncthreads();
        if (tid < 2) {
            float s = 0.f;
            for (int m = 0; m < 32; ++m) s += tmpv[tid * 32 + m];
            invq[tid] = 1.f / fmaxf(sqrtf(s), 1e-8f);
        }
        __syncthreads();
        if (tid < 144) {            // phase-1 NAND rows
            float d1 = 0.f, d2 = 0.f;
            for (int m = 0; m < 32; ++m) {
                d1 += pk[m]      * sG[m * 208 + tid];
                d2 += pk[32 + m] * sG[(32 + m) * 208 + tid];
            }
            float i1 = sA[tid * 2]     * fabsf(d1) * invq[0] + sB[tid * 2];
            float i2 = sA[tid * 2 + 1] * fabsf(d2) * invq[1] + sB[tid * 2 + 1];
            nnd[tid] = i0[tid] * i1 * i2;
        }
        __syncthreads();
        if (tid < 4) {              // pop / push gates
            int k = tid >> 1, which = tid & 1;
            int base = (which ? 8 : 0) + 4 * k;
            float sp = fmaxf(nnd[base], nnd[base + 1]);
            float sn = fmaxf(nnd[base + 2], nnd[base + 3]);
            float sh = ssh[k];
            float e0 = expf(sp * sh), e1 = expf(sn * sh);
            float p0 = e0 / (e0 + e1);
            gate[k][which * 2] = p0; gate[k][which * 2 + 1] = 1.f - p0;
        }
        if (tid >= 64 && tid < 128) {  // push_fn pair sums
            int idx = tid - 64; int k = idx >> 5, o = idx & 31;
            pvs[idx] = nnd[16 + 64 * k + 2 * o] + nnd[16 + 64 * k + 2 * o + 1];
        }
        __syncthreads();
        if (tid < 64) {             // push_val coords (old peeks)
            int k = tid >> 5, m = tid & 31;
            float v = pvs[k * 32 + 30] * pk[m] + pvs[k * 32 + 31] * pk[32 + m];
            if (m >= 2) v += pvs[k * 32 + m - 2];
            pvc[tid] = v;
        }
        __syncthreads();
        {                           // stack update: pop_or_nop then push_or_nop
            int k = tid >> 7, d = (tid >> 5) & 3, m = tid & 31;
            float prp0 = gate[k][0], prp1 = gate[k][1];
            float prq0 = gate[k][2], prq1 = gate[k][3];
            float pd   = sptr[k * 4 + d];
            float pdp1 = sptr[k * 4 + ((d + 1) & 3)];
            float pdm1 = sptr[k * 4 + ((d + 3) & 3)];
            float sold = st[(k * 4 + d) * 32 + m];
            float ps = sold * (1.f - pd) + ((m == 0) ? ZOFF : 0.f) * pd;
            float s1 = ps * prp0 + sold * prp1;
            float p1_d   = pdp1 * prp0 + pd * prp1;
            float p1_dm1 = pd * prp0 + pdm1 * prp1;   // p1 at slot d-1
            float pu = p1_dm1;                         // roll(+1) at slot d
            float su = s1 * (1.f - pu) + pvc[k * 32 + m] * pu;
            float s2 = su * prq0 + s1 * prq1;
            float p2 = pu * prq0 + p1_d * prq1;
            __syncthreads();
            st[(k * 4 + d) * 32 + m] = s2;
            if (m == 0) sptr[k * 4 + d] = p2;
        }
        __syncthreads();
        // ---- phase 2 ----
        if (tid < 64) {
            int k = tid >> 5, m = tid & 31;
            float s = 0.f;
            for (int d = 0; d < 4; ++d) s += st[(k * 4 + d) * 32 + m] * sptr[k * 4 + d];
            pk[tid] = s;
        }
        __syncthreads();
        if (tid < 64) {
            int k = tid >> 5, m = tid & 31;
            float s = 0.f;
            for (int mm = 0; mm < 32; ++mm) s += sM[m * 33 + mm] * pk[k * 32 + mm];
            tmpv[tid] = s * pk[tid];
        }
        __syncthreads();
        if (tid < 2) {
            float s = 0.f;
            for (int m = 0; m < 32; ++m) s += tmpv[tid * 32 + m];
            invq[tid] = 1.f / fmaxf(sqrtf(s), 1e-8f);
        }
        __syncthreads();
        if (tid < 64) {             // calc rows
            int c = 144 + tid;
            float d1 = 0.f, d2 = 0.f;
            for (int m = 0; m < 32; ++m) {
                d1 += pk[m]      * sG[m * 208 + c];
                d2 += pk[32 + m] * sG[(32 + m) * 208 + c];
            }
            float i1 = sA[c * 2]     * fabsf(d1) * invq[0] + sB[c * 2];
            float i2 = sA[c * 2 + 1] * fabsf(d2) * invq[1] + sB[c * 2 + 1];
            nnd[c] = i0[c] * i1 * i2;
        }
        __syncthreads();
        if (tid < 32) pvs[tid] = nnd[144 + 2 * tid] + nnd[144 + 2 * tid + 1];
        __syncthreads();
        if (tid < 32) {             // output coords
            int m = tid;
            float v = pvs[30] * pk[m] + pvs[31] * pk[32 + m];
            if (m >= 2) v += pvs[m - 2];
            ws[OFF_OC + bt * 32 + m] = v;
        }
        __syncthreads();
    }
}

// ---------------- kernel D: expand coords -> 512-dim output ----------------
__global__ __launch_bounds__(256) void kD(const float* __restrict__ ws, const float* __restrict__ syms,
                                          const float* __restrict__ siv, float* __restrict__ out) {
    __shared__ float bas[31 * 512];   // m=0: siv, m=1..30: syms
    __shared__ float ocr[32];
    int blk = blockIdx.x, tid = threadIdx.x;
    for (int i = tid; i < 31 * 512; i += 256) {
        int m = i >> 9, v = i & 511;
        bas[i] = (m == 0) ? siv[v] : syms[(m - 1) * 512 + v];
    }
    __syncthreads();
    for (int r = 0; r < 128; ++r) {
        size_t bt = (size_t)blk * 128 + r;
        if (tid < 32) ocr[tid] = ws[OFF_OC + bt * 32 + tid];
        __syncthreads();
        int v = tid * 2;
        float s0 = ocr[0], s1 = ocr[0];   // ones-basis contribution
        for (int m = 0; m < 31; ++m) {
            float c = ocr[m + 1];
            s0 += c * bas[m * 512 + v];
            s1 += c * bas[m * 512 + v + 1];
        }
        ((float2*)out)[bt * 256 + tid] = make_float2(s0, s1);
        __syncthreads();
    }
}

extern "C" void kernel_launch(void* const* d_in, const int* in_sizes, int n_in,
                              void* d_out, int out_size, void* d_ws, size_t ws_size,
                              hipStream_t stream) {
    const float* x    = (const float*)d_in[0];
    const float* syms = (const float*)d_in[1];
    const float* siv  = (const float*)d_in[2];
    const float* shp  = (const float*)d_in[3];
    const float* pw   = (const float*)d_in[4];
    const float* pn   = (const float*)d_in[5];
    const float* pow_ = (const float*)d_in[6];
    const float* pon  = (const float*)d_in[7];
    const float* pfw  = (const float*)d_in[8];
    const float* pfn  = (const float*)d_in[9];
    const float* cw   = (const float*)d_in[10];
    const float* cn   = (const float*)d_in[11];
    float* ws  = (float*)d_ws;
    float* out = (float*)d_out;

    hipLaunchKernelGGL(kB, dim3(68),   dim3(256), 0, stream,
                       syms, siv, pw, pn, pow_, pon, pfw, pfn, cw, cn, ws);
    hipLaunchKernelGGL(kA, dim3(512),  dim3(256), 0, stream, x, ws);
    hipLaunchKernelGGL(kC, dim3(256),  dim3(256), 0, stream, ws, shp);
    hipLaunchKernelGGL(kD, dim3(256),  dim3(256), 0, stream, ws, syms, siv, out);
}

// Round 3
// 794.606 us; speedup vs baseline: 1.9088x; 1.1243x over previous
//
#include <hip/hip_runtime.h>
#include <math.h>

// Cyborg stack machine: B=256, S=128, V=512, H=30, N_STACKS=2, R=2, DEPTH=4
// All stack/peek/output vectors live in span{ones, init_vec, syms0..29} (32-dim).
// kC: ONE WAVE PER BATCH (64-thread blocks) — wave-synchronous, 4 cheap fences/step.

#define SS 128
#define VV 512
#define NROWS 208      // 8 pop + 8 pushop + 128 pushfn + 64 calc
#define ZOFF 1e-6f

// ws layout (float offsets)
#define OFF_I0   0                          // interp0: 32768*208
#define OFF_OC   (32768*208)                // out coords: 32768*32
#define OFF_GI   (OFF_OC + 32768*32)        // swizzled G: 208 rows * 64 floats
#define OFF_M    (OFF_GI + 208*64)          // Gram 32*32
#define OFF_A    (OFF_M + 1024)             // A coef 208*3
#define OFF_Bc   (OFF_A + 624)              // B coef 208*3
#define OFF_W0   (OFF_Bc + 624)             // gathered w j=0 slice [208][512]

__device__ __forceinline__ const float* w_row(int r, const float* pw, const float* pow_,
                                              const float* pfw, const float* cw) {
    if (r < 8)   return pw   + r * 1536;
    if (r < 16)  return pow_ + (r - 8) * 1536;
    if (r < 144) return pfw  + (r - 16) * 1536;
    return cw + (r - 144) * 1536;
}
__device__ __forceinline__ const float* nw_row(int r, const float* pn, const float* pon,
                                               const float* pfn, const float* cn) {
    if (r < 8)   return pn   + r * 3;
    if (r < 16)  return pon  + (r - 8) * 3;
    if (r < 144) return pfn  + (r - 16) * 3;
    return cn + (r - 144) * 3;
}

// ---------------- kernel B: precompute tables ----------------
__global__ void kB(const float* __restrict__ syms, const float* __restrict__ siv,
                   const float* __restrict__ pw, const float* __restrict__ pn,
                   const float* __restrict__ pow_, const float* __restrict__ pon,
                   const float* __restrict__ pfw, const float* __restrict__ pfn,
                   const float* __restrict__ cw, const float* __restrict__ cn,
                   float* __restrict__ ws) {
    int blk = blockIdx.x, tid = threadIdx.x;
    if (blk < 64) {
        // G[jj][e][c] = basis_e . w_row(c)[(jj+1)*512 ..); store swizzled+interleaved:
        // float offset = c*64 + ((e>>1)^(c&15))*4 + (e&1)*2 + jj
        int jj = blk >> 5, e = blk & 31;
        __shared__ float bas[512];
        for (int i = tid; i < 512; i += 256)
            bas[i] = (e == 0) ? 1.0f : ((e == 1) ? siv[i] : syms[(e - 2) * 512 + i]);
        __syncthreads();
        if (tid < NROWS) {
            int c = tid;
            const float4* w4 = (const float4*)(w_row(c, pw, pow_, pfw, cw) + (jj + 1) * 512);
            const float4* b4 = (const float4*)bas;
            float s = 0.f;
            for (int q = 0; q < 128; ++q) {
                float4 a = b4[q], b = w4[q];
                s += a.x * b.x + a.y * b.y + a.z * b.z + a.w * b.w;
            }
            ws[OFF_GI + c * 64 + (((e >> 1) ^ (c & 15)) << 2) + ((e & 1) << 1) + jj] = s;
        }
    } else if (blk == 64) {
        // Gram M[m][mm]
        __shared__ float basw[32 * 512];
        for (int i = tid; i < 32 * 512; i += 256) {
            int m = i >> 9, v = i & 511;
            basw[i] = (m == 0) ? 1.0f : ((m == 1) ? siv[v] : syms[(m - 2) * 512 + v]);
        }
        __syncthreads();
        for (int p = tid; p < 1024; p += 256) {
            int m = p >> 5, mm = p & 31;
            const float4* a4 = (const float4*)(basw + m * 512);
            const float4* b4 = (const float4*)(basw + mm * 512);
            float s = 0.f;
            for (int q = 0; q < 128; ++q) {
                float4 a = a4[q], b = b4[q];
                s += a.x * b.x + a.y * b.y + a.z * b.z + a.w * b.w;
            }
            ws[OFF_M + p] = s;
        }
    } else if (blk == 65) {
        // folded NAND coefs: A=(2*sig-1)/||w||, B=1-sig   for (r, j)
        for (int idx = tid; idx < 624; idx += 256) {
            int r = idx / 3, j = idx % 3;
            const float4* w4 = (const float4*)(w_row(r, pw, pow_, pfw, cw) + j * 512);
            float s = 0.f;
            for (int q = 0; q < 128; ++q) {
                float4 b = w4[q];
                s += b.x * b.x + b.y * b.y + b.z * b.z + b.w * b.w;
            }
            float nrm = fmaxf(sqrtf(s), 1e-8f);
            float nwv = nw_row(r, pn, pon, pfn, cn)[j];
            float sig = 1.f / (1.f + expf(-nwv));
            ws[OFF_A + idx]  = (2.f * sig - 1.f) / nrm;
            ws[OFF_Bc + idx] = 1.f - sig;
        }
    } else {
        // gather w j=0 slice into contiguous [208][512] — 16 blocks
        int part = blk - 66;
        for (int i = tid; i < 6656; i += 256) {
            int flat = part * 6656 + i;
            int c = flat >> 9, v = flat & 511;
            ws[OFF_W0 + flat] = w_row(c, pw, pow_, pfw, cw)[v];
        }
    }
}

// ---------------- kernel A: interp0 via LDS-tiled f32 GEMM ----------------
__global__ __launch_bounds__(256) void kA(const float* __restrict__ x, float* __restrict__ ws) {
    __shared__ float xs[64 * 36];
    __shared__ float wsh[208 * 36];
    __shared__ float red[256];
    __shared__ float invx[64];
    int blk = blockIdx.x, tid = threadIdx.x;
    size_t bt0 = (size_t)blk * 64;

    {
        int r = tid >> 2, seg = tid & 3;
        const float4* xr = (const float4*)(x + (bt0 + r) * 512 + seg * 128);
        float s = 0.f;
        for (int q = 0; q < 32; ++q) {
            float4 a = xr[q];
            s += a.x * a.x + a.y * a.y + a.z * a.z + a.w * a.w;
        }
        red[tid] = s;
    }
    __syncthreads();
    if (tid < 64) {
        float s = red[tid * 4] + red[tid * 4 + 1] + red[tid * 4 + 2] + red[tid * 4 + 3];
        invx[tid] = 1.f / fmaxf(sqrtf(s), 1e-8f);
    }

    int tx = tid & 15, ty = tid >> 4;
    float acc[4][13];
    for (int rr = 0; rr < 4; ++rr)
        for (int j = 0; j < 13; ++j) acc[rr][j] = 0.f;

    const float* w0 = ws + OFF_W0;
    for (int kt = 0; kt < 16; ++kt) {
        __syncthreads();
        for (int it = 0; it < 8; ++it) {
            int i = tid + 256 * it;
            int r = i >> 5, kk = i & 31;
            xs[r * 36 + kk] = x[(bt0 + r) * 512 + kt * 32 + kk];
        }
        for (int i = tid; i < 6656; i += 256) {
            int c = i >> 5, kk = i & 31;
            wsh[c * 36 + kk] = w0[c * 512 + kt * 32 + kk];
        }
        __syncthreads();
        for (int g = 0; g < 8; ++g) {
            int k = g * 4;
            float4 a4[4], b4[13];
            for (int rr = 0; rr < 4; ++rr)
                a4[rr] = *(const float4*)(xs + (ty * 4 + rr) * 36 + k);
            for (int j = 0; j < 13; ++j)
                b4[j] = *(const float4*)(wsh + (tx + 16 * j) * 36 + k);
            for (int rr = 0; rr < 4; ++rr)
                for (int j = 0; j < 13; ++j) {
                    float4 a = a4[rr], b = b4[j];
                    acc[rr][j] += a.x * b.x + a.y * b.y + a.z * b.z + a.w * b.w;
                }
        }
    }
    for (int rr = 0; rr < 4; ++rr) {
        int r = ty * 4 + rr;
        float ix = invx[r];
        size_t row = (bt0 + r) * 208;
        for (int j = 0; j < 13; ++j) {
            int c = tx + 16 * j;
            float A0 = ws[OFF_A + c * 3];
            float B0 = ws[OFF_Bc + c * 3];
            ws[OFF_I0 + row + c] = A0 * fabsf(acc[rr][j]) * ix + B0;
        }
    }
}

// ---------------- kernel C: wave-per-batch recurrence in coord space ----------------
// Lane l: k = l>>5 (stack), m = l&31 (basis coord). Row slots: {l, 64+l, 128+l (l<16), 144+l}.
__global__ __launch_bounds__(64) void kC(float* __restrict__ ws, const float* __restrict__ sharp) {
    __shared__ float sGI[208 * 64];
    __shared__ float pkL[64];
    __shared__ float nndL[16];
    __shared__ float nndP[128];
    __shared__ float nnd2[64];
    const int b = blockIdx.x, l = threadIdx.x;
    const int k = l >> 5, m = l & 31, sw = l & 15;

    for (int i = l; i < 13312; i += 64) sGI[i] = ws[OFF_GI + i];

    float Mrow[32];
#pragma unroll
    for (int q = 0; q < 8; ++q) {
        float4 f = *(const float4*)(ws + OFF_M + m * 32 + q * 4);
        Mrow[4*q] = f.x; Mrow[4*q+1] = f.y; Mrow[4*q+2] = f.z; Mrow[4*q+3] = f.w;
    }
    int rows[4];
    rows[0] = l; rows[1] = 64 + l; rows[2] = (l < 16) ? (128 + l) : l; rows[3] = 144 + l;
    float A1[4], A2[4], B1[4], B2[4];
#pragma unroll
    for (int s = 0; s < 4; ++s) {
        A1[s] = ws[OFF_A + rows[s] * 3 + 1];
        A2[s] = ws[OFF_A + rows[s] * 3 + 2];
        B1[s] = ws[OFF_Bc + rows[s] * 3 + 1];
        B2[s] = ws[OFF_Bc + rows[s] * 3 + 2];
    }
    const float sh = sharp[k];

    float st[4], p[4];
#pragma unroll
    for (int d = 0; d < 4; ++d) {
        st[d] = (d == 1) ? ((m == 1) ? 1.f : 0.f) : ((m == 0) ? ZOFF : 0.f);
        p[d] = (d == 1) ? 1.f : 0.f;
    }
    const float* i0base = ws + OFF_I0 + (size_t)b * SS * 208;
    float i0c[4];
#pragma unroll
    for (int s = 0; s < 4; ++s) i0c[s] = i0base[rows[s]];
    __syncthreads();

    for (int t = 0; t < SS; ++t) {
        // prefetch next step's i0 (overlaps ~whole step)
        const float* nb = i0base + (size_t)((t < SS - 1) ? (t + 1) : t) * 208;
        float i0n0 = nb[rows[0]], i0n1 = nb[rows[1]], i0n2 = nb[rows[2]], i0n3 = nb[rows[3]];

        // ---- phase 1 ----
        float pk = st[0]*p[0] + st[1]*p[1] + st[2]*p[2] + st[3]*p[3];
        pkL[l] = pk;
        __syncthreads();
        float p0b[32], p1b[32];
#pragma unroll
        for (int q = 0; q < 8; ++q) {
            float4 f = *(const float4*)(pkL + 4 * q);
            p0b[4*q] = f.x; p0b[4*q+1] = f.y; p0b[4*q+2] = f.z; p0b[4*q+3] = f.w;
        }
#pragma unroll
        for (int q = 0; q < 8; ++q) {
            float4 f = *(const float4*)(pkL + 32 + 4 * q);
            p1b[4*q] = f.x; p1b[4*q+1] = f.y; p1b[4*q+2] = f.z; p1b[4*q+3] = f.w;
        }
        // Gram norms
        float Mv0 = 0.f, Mv1 = 0.f;
#pragma unroll
        for (int i = 0; i < 32; ++i) { Mv0 += Mrow[i] * p0b[i]; Mv1 += Mrow[i] * p1b[i]; }
        float part = pk * (k ? Mv1 : Mv0);
        part += __shfl_xor(part, 1);  part += __shfl_xor(part, 2);
        part += __shfl_xor(part, 4);  part += __shfl_xor(part, 8);
        part += __shfl_xor(part, 16);
        float q0 = __shfl(part, 0), q1 = __shfl(part, 32);
        float iq0 = 1.f / fmaxf(sqrtf(q0), 1e-8f);
        float iq1 = 1.f / fmaxf(sqrtf(q1), 1e-8f);
        // NAND dots, slots 0/1 (all lanes) + slot 2 (l<16)
        float nv0, nv1;
        {
            const float* gp = sGI + rows[0] * 64;
            float d1 = 0.f, d2 = 0.f;
#pragma unroll
            for (int q = 0; q < 16; ++q) {
                float4 g = *(const float4*)(gp + ((q ^ sw) << 2));
                d1 += p0b[2*q] * g.x + p0b[2*q+1] * g.z;
                d2 += p1b[2*q] * g.y + p1b[2*q+1] * g.w;
            }
            nv0 = i0c[0] * (A1[0]*fabsf(d1)*iq0 + B1[0]) * (A2[0]*fabsf(d2)*iq1 + B2[0]);
        }
        {
            const float* gp = sGI + rows[1] * 64;
            float d1 = 0.f, d2 = 0.f;
#pragma unroll
            for (int q = 0; q < 16; ++q) {
                float4 g = *(const float4*)(gp + ((q ^ sw) << 2));
                d1 += p0b[2*q] * g.x + p0b[2*q+1] * g.z;
                d2 += p1b[2*q] * g.y + p1b[2*q+1] * g.w;
            }
            nv1 = i0c[1] * (A1[1]*fabsf(d1)*iq0 + B1[1]) * (A2[1]*fabsf(d2)*iq1 + B2[1]);
        }
        if (l < 16) {
            const float* gp = sGI + rows[2] * 64;
            float d1 = 0.f, d2 = 0.f;
#pragma unroll
            for (int q = 0; q < 16; ++q) {
                float4 g = *(const float4*)(gp + ((q ^ sw) << 2));
                d1 += p0b[2*q] * g.x + p0b[2*q+1] * g.z;
                d2 += p1b[2*q] * g.y + p1b[2*q+1] * g.w;
            }
            nndP[112 + l] = i0c[2] * (A1[2]*fabsf(d1)*iq0 + B1[2]) * (A2[2]*fabsf(d2)*iq1 + B2[2]);
            nndL[l] = nv0;
        } else {
            nndP[l - 16] = nv0;
        }
        nndP[48 + l] = nv1;
        __syncthreads();
        // gates (redundant per lane, from its k)
        float4 gp4 = *(const float4*)(nndL + 4 * k);
        float4 gq4 = *(const float4*)(nndL + 8 + 4 * k);
        float prp0 = 1.f / (1.f + __expf((fmaxf(gp4.z, gp4.w) - fmaxf(gp4.x, gp4.y)) * sh));
        float prq0 = 1.f / (1.f + __expf((fmaxf(gq4.z, gq4.w) - fmaxf(gq4.x, gq4.y)) * sh));
        float prp1 = 1.f - prp0, prq1 = 1.f - prq0;
        // push_val coord (lane-local m)
        float prx = 0.f, pry = 0.f;
        if (m >= 2) {
            float2 pr2 = *(const float2*)(nndP + 64 * k + 2 * m - 4);
            prx = pr2.x; pry = pr2.y;
        }
        float4 t30 = *(const float4*)(nndP + 64 * k + 60);
        float pk0m = __shfl(pk, m), pk1m = __shfl(pk, 32 + m);
        float pvc = prx + pry + (t30.x + t30.y) * pk0m + (t30.z + t30.w) * pk1m;
        // stack update (all register-local)
        float zc = (m == 0) ? ZOFF : 0.f;
        float s1[4], p1[4];
#pragma unroll
        for (int d = 0; d < 4; ++d) {
            float ps = st[d] * (1.f - p[d]) + zc * p[d];
            s1[d] = ps * prp0 + st[d] * prp1;
            p1[d] = p[(d + 1) & 3] * prp0 + p[d] * prp1;
        }
        float pn_[4];
#pragma unroll
        for (int d = 0; d < 4; ++d) {
            float pu = p1[(d + 3) & 3];
            float su = s1[d] * (1.f - pu) + pvc * pu;
            st[d] = su * prq0 + s1[d] * prq1;
            pn_[d] = pu * prq0 + p1[d] * prq1;
        }
#pragma unroll
        for (int d = 0; d < 4; ++d) p[d] = pn_[d];

        // ---- phase 2 ----
        float pk2 = st[0]*p[0] + st[1]*p[1] + st[2]*p[2] + st[3]*p[3];
        pkL[l] = pk2;
        __syncthreads();
#pragma unroll
        for (int q = 0; q < 8; ++q) {
            float4 f = *(const float4*)(pkL + 4 * q);
            p0b[4*q] = f.x; p0b[4*q+1] = f.y; p0b[4*q+2] = f.z; p0b[4*q+3] = f.w;
        }
#pragma unroll
        for (int q = 0; q < 8; ++q) {
            float4 f = *(const float4*)(pkL + 32 + 4 * q);
            p1b[4*q] = f.x; p1b[4*q+1] = f.y; p1b[4*q+2] = f.z; p1b[4*q+3] = f.w;
        }
        Mv0 = 0.f; Mv1 = 0.f;
#pragma unroll
        for (int i = 0; i < 32; ++i) { Mv0 += Mrow[i] * p0b[i]; Mv1 += Mrow[i] * p1b[i]; }
        part = pk2 * (k ? Mv1 : Mv0);
        part += __shfl_xor(part, 1);  part += __shfl_xor(part, 2);
        part += __shfl_xor(part, 4);  part += __shfl_xor(part, 8);
        part += __shfl_xor(part, 16);
        q0 = __shfl(part, 0); q1 = __shfl(part, 32);
        iq0 = 1.f / fmaxf(sqrtf(q0), 1e-8f);
        iq1 = 1.f / fmaxf(sqrtf(q1), 1e-8f);
        {
            const float* gp = sGI + rows[3] * 64;
            float d1 = 0.f, d2 = 0.f;
#pragma unroll
            for (int q = 0; q < 16; ++q) {
                float4 g = *(const float4*)(gp + ((q ^ sw) << 2));
                d1 += p0b[2*q] * g.x + p0b[2*q+1] * g.z;
                d2 += p1b[2*q] * g.y + p1b[2*q+1] * g.w;
            }
            nnd2[l] = i0c[3] * (A1[3]*fabsf(d1)*iq0 + B1[3]) * (A2[3]*fabsf(d2)*iq1 + B2[3]);
        }
        __syncthreads();
        float cx = 0.f, cy = 0.f;
        if (m >= 2) {
            float2 c2 = *(const float2*)(nnd2 + 2 * m - 4);
            cx = c2.x; cy = c2.y;
        }
        float4 c30 = *(const float4*)(nnd2 + 60);
        float pk0m2 = __shfl(pk2, m), pk1m2 = __shfl(pk2, 32 + m);
        float oc = cx + cy + (c30.x + c30.y) * pk0m2 + (c30.z + c30.w) * pk1m2;
        if (l < 32) ws[OFF_OC + ((size_t)b * SS + t) * 32 + m] = oc;
        i0c[0] = i0n0; i0c[1] = i0n1; i0c[2] = i0n2; i0c[3] = i0n3;
        __syncthreads();
    }
}

// ---------------- kernel D: expand coords -> 512-dim output (barrier-free) ----------------
// grid 2048 blocks x 256 threads: block = 16 rows; wave rg = t>>6 handles rows r0..r0+3;
// lane handles 8 consecutive v. All operands from global (syms 60KB L2-resident).
__global__ __launch_bounds__(256) void kD(const float* __restrict__ ws, const float* __restrict__ syms,
                                          const float* __restrict__ siv, float* __restrict__ out) {
    int t = threadIdx.x;
    int rg = t >> 6;
    int vc = (t & 63) * 8;
    size_t r0 = (size_t)blockIdx.x * 16 + rg * 4;
    const float* oc = ws + OFF_OC;
    float acc[4][8];
    float4 sv0 = *(const float4*)(siv + vc);
    float4 sv1 = *(const float4*)(siv + vc + 4);
#pragma unroll
    for (int rr = 0; rr < 4; ++rr) {
        float c0 = oc[(r0 + rr) * 32 + 0];
        float c1 = oc[(r0 + rr) * 32 + 1];
        acc[rr][0] = c0 + c1 * sv0.x; acc[rr][1] = c0 + c1 * sv0.y;
        acc[rr][2] = c0 + c1 * sv0.z; acc[rr][3] = c0 + c1 * sv0.w;
        acc[rr][4] = c0 + c1 * sv1.x; acc[rr][5] = c0 + c1 * sv1.y;
        acc[rr][6] = c0 + c1 * sv1.z; acc[rr][7] = c0 + c1 * sv1.w;
    }
    for (int mm = 0; mm < 30; ++mm) {
        float4 b0 = *(const float4*)(syms + mm * 512 + vc);
        float4 b1 = *(const float4*)(syms + mm * 512 + vc + 4);
#pragma unroll
        for (int rr = 0; rr < 4; ++rr) {
            float c = oc[(r0 + rr) * 32 + 2 + mm];
            acc[rr][0] += c * b0.x; acc[rr][1] += c * b0.y;
            acc[rr][2] += c * b0.z; acc[rr][3] += c * b0.w;
            acc[rr][4] += c * b1.x; acc[rr][5] += c * b1.y;
            acc[rr][6] += c * b1.z; acc[rr][7] += c * b1.w;
        }
    }
#pragma unroll
    for (int rr = 0; rr < 4; ++rr) {
        float* o = out + (r0 + rr) * 512 + vc;
        *(float4*)o       = make_float4(acc[rr][0], acc[rr][1], acc[rr][2], acc[rr][3]);
        *(float4*)(o + 4) = make_float4(acc[rr][4], acc[rr][5], acc[rr][6], acc[rr][7]);
    }
}

extern "C" void kernel_launch(void* const* d_in, const int* in_sizes, int n_in,
                              void* d_out, int out_size, void* d_ws, size_t ws_size,
                              hipStream_t stream) {
    const float* x    = (const float*)d_in[0];
    const float* syms = (const float*)d_in[1];
    const float* siv  = (const float*)d_in[2];
    const float* shp  = (const float*)d_in[3];
    const float* pw   = (const float*)d_in[4];
    const float* pn   = (const float*)d_in[5];
    const float* pow_ = (const float*)d_in[6];
    const float* pon  = (const float*)d_in[7];
    const float* pfw  = (const float*)d_in[8];
    const float* pfn  = (const float*)d_in[9];
    const float* cw   = (const float*)d_in[10];
    const float* cn   = (const float*)d_in[11];
    float* ws  = (float*)d_ws;
    float* out = (float*)d_out;

    hipLaunchKernelGGL(kB, dim3(82),   dim3(256), 0, stream,
                       syms, siv, pw, pn, pow_, pon, pfw, pfn, cw, cn, ws);
    hipLaunchKernelGGL(kA, dim3(512),  dim3(256), 0, stream, x, ws);
    hipLaunchKernelGGL(kC, dim3(256),  dim3(64),  0, stream, ws, shp);
    hipLaunchKernelGGL(kD, dim3(2048), dim3(256), 0, stream, ws, syms, siv, out);
}

// Round 4
// 705.339 us; speedup vs baseline: 2.1504x; 1.1266x over previous
//
#include <hip/hip_runtime.h>
#include <math.h>

// Cyborg stack machine: B=256, S=128, V=512, H=30, N_STACKS=2, R=2, DEPTH=4
// All stack/peek/output vectors live in span{ones, init_vec, syms0..29} (32-dim).
// kC: one wave per batch chain; G table entirely in VGPRs (occupancy is 1 wave/CU
// anyway, so registers are free). LDS only for pk broadcast + nnd exchange.

#define SS 128
#define VV 512
#define NROWS 208      // 8 pop + 8 pushop + 128 pushfn + 64 calc
#define ZOFF 1e-6f

// ws layout (float offsets)
#define OFF_I0   0                          // interp0: 32768*208
#define OFF_OC   (32768*208)                // out coords: 32768*32
#define OFF_GI   (OFF_OC + 32768*32)        // G[2][32][208]  (stack, basis, row)
#define OFF_M    (OFF_GI + 2*32*208)        // Gram 32*32
#define OFF_A    (OFF_M + 1024)             // A coef 208*3
#define OFF_Bc   (OFF_A + 624)              // B coef 208*3
#define OFF_W0   (OFF_Bc + 624)             // gathered w j=0 slice [208][512]

__device__ __forceinline__ const float* w_row(int r, const float* pw, const float* pow_,
                                              const float* pfw, const float* cw) {
    if (r < 8)   return pw   + r * 1536;
    if (r < 16)  return pow_ + (r - 8) * 1536;
    if (r < 144) return pfw  + (r - 16) * 1536;
    return cw + (r - 144) * 1536;
}
__device__ __forceinline__ const float* nw_row(int r, const float* pn, const float* pon,
                                               const float* pfn, const float* cn) {
    if (r < 8)   return pn   + r * 3;
    if (r < 16)  return pon  + (r - 8) * 3;
    if (r < 144) return pfn  + (r - 16) * 3;
    return cn + (r - 144) * 3;
}

// ---------------- kernel B: precompute tables ----------------
__global__ void kB(const float* __restrict__ syms, const float* __restrict__ siv,
                   const float* __restrict__ pw, const float* __restrict__ pn,
                   const float* __restrict__ pow_, const float* __restrict__ pon,
                   const float* __restrict__ pfw, const float* __restrict__ pfn,
                   const float* __restrict__ cw, const float* __restrict__ cn,
                   float* __restrict__ ws) {
    int blk = blockIdx.x, tid = threadIdx.x;
    if (blk < 64) {
        // G[jj][e][c] = basis_e . w_row(c)[(jj+1)*512 ..)
        int jj = blk >> 5, e = blk & 31;
        __shared__ float bas[512];
        for (int i = tid; i < 512; i += 256)
            bas[i] = (e == 0) ? 1.0f : ((e == 1) ? siv[i] : syms[(e - 2) * 512 + i]);
        __syncthreads();
        if (tid < NROWS) {
            int c = tid;
            const float4* w4 = (const float4*)(w_row(c, pw, pow_, pfw, cw) + (jj + 1) * 512);
            const float4* b4 = (const float4*)bas;
            float s = 0.f;
            for (int q = 0; q < 128; ++q) {
                float4 a = b4[q], b = w4[q];
                s += a.x * b.x + a.y * b.y + a.z * b.z + a.w * b.w;
            }
            ws[OFF_GI + (jj * 32 + e) * 208 + c] = s;
        }
    } else if (blk == 64) {
        // Gram M[m][mm]
        __shared__ float basw[32 * 512];
        for (int i = tid; i < 32 * 512; i += 256) {
            int m = i >> 9, v = i & 511;
            basw[i] = (m == 0) ? 1.0f : ((m == 1) ? siv[v] : syms[(m - 2) * 512 + v]);
        }
        __syncthreads();
        for (int p = tid; p < 1024; p += 256) {
            int m = p >> 5, mm = p & 31;
            const float4* a4 = (const float4*)(basw + m * 512);
            const float4* b4 = (const float4*)(basw + mm * 512);
            float s = 0.f;
            for (int q = 0; q < 128; ++q) {
                float4 a = a4[q], b = b4[q];
                s += a.x * b.x + a.y * b.y + a.z * b.z + a.w * b.w;
            }
            ws[OFF_M + p] = s;
        }
    } else if (blk == 65) {
        // folded NAND coefs: A=(2*sig-1)/||w||, B=1-sig   for (r, j)
        for (int idx = tid; idx < 624; idx += 256) {
            int r = idx / 3, j = idx % 3;
            const float4* w4 = (const float4*)(w_row(r, pw, pow_, pfw, cw) + j * 512);
            float s = 0.f;
            for (int q = 0; q < 128; ++q) {
                float4 b = w4[q];
                s += b.x * b.x + b.y * b.y + b.z * b.z + b.w * b.w;
            }
            float nrm = fmaxf(sqrtf(s), 1e-8f);
            float nwv = nw_row(r, pn, pon, pfn, cn)[j];
            float sig = 1.f / (1.f + expf(-nwv));
            ws[OFF_A + idx]  = (2.f * sig - 1.f) / nrm;
            ws[OFF_Bc + idx] = 1.f - sig;
        }
    } else {
        // gather w j=0 slice into contiguous [208][512] — 16 blocks
        int part = blk - 66;
        for (int i = tid; i < 6656; i += 256) {
            int flat = part * 6656 + i;
            int c = flat >> 9, v = flat & 511;
            ws[OFF_W0 + flat] = w_row(c, pw, pow_, pfw, cw)[v];
        }
    }
}

// ---------------- kernel A: interp0 via LDS-tiled f32 GEMM ----------------
__global__ __launch_bounds__(256) void kA(const float* __restrict__ x, float* __restrict__ ws) {
    __shared__ float xs[64 * 36];
    __shared__ float wsh[208 * 36];
    __shared__ float red[256];
    __shared__ float invx[64];
    int blk = blockIdx.x, tid = threadIdx.x;
    size_t bt0 = (size_t)blk * 64;

    {
        int r = tid >> 2, seg = tid & 3;
        const float4* xr = (const float4*)(x + (bt0 + r) * 512 + seg * 128);
        float s = 0.f;
        for (int q = 0; q < 32; ++q) {
            float4 a = xr[q];
            s += a.x * a.x + a.y * a.y + a.z * a.z + a.w * a.w;
        }
        red[tid] = s;
    }
    __syncthreads();
    if (tid < 64) {
        float s = red[tid * 4] + red[tid * 4 + 1] + red[tid * 4 + 2] + red[tid * 4 + 3];
        invx[tid] = 1.f / fmaxf(sqrtf(s), 1e-8f);
    }

    int tx = tid & 15, ty = tid >> 4;
    float acc[4][13];
    for (int rr = 0; rr < 4; ++rr)
        for (int j = 0; j < 13; ++j) acc[rr][j] = 0.f;

    const float* w0 = ws + OFF_W0;
    for (int kt = 0; kt < 16; ++kt) {
        __syncthreads();
        for (int it = 0; it < 8; ++it) {
            int i = tid + 256 * it;
            int r = i >> 5, kk = i & 31;
            xs[r * 36 + kk] = x[(bt0 + r) * 512 + kt * 32 + kk];
        }
        for (int i = tid; i < 6656; i += 256) {
            int c = i >> 5, kk = i & 31;
            wsh[c * 36 + kk] = w0[c * 512 + kt * 32 + kk];
        }
        __syncthreads();
        for (int g = 0; g < 8; ++g) {
            int k = g * 4;
            float4 a4[4], b4[13];
            for (int rr = 0; rr < 4; ++rr)
                a4[rr] = *(const float4*)(xs + (ty * 4 + rr) * 36 + k);
            for (int j = 0; j < 13; ++j)
                b4[j] = *(const float4*)(wsh + (tx + 16 * j) * 36 + k);
            for (int rr = 0; rr < 4; ++rr)
                for (int j = 0; j < 13; ++j) {
                    float4 a = a4[rr], b = b4[j];
                    acc[rr][j] += a.x * b.x + a.y * b.y + a.z * b.z + a.w * b.w;
                }
        }
    }
    for (int rr = 0; rr < 4; ++rr) {
        int r = ty * 4 + rr;
        float ix = invx[r];
        size_t row = (bt0 + r) * 208;
        for (int j = 0; j < 13; ++j) {
            int c = tx + 16 * j;
            float A0 = ws[OFF_A + c * 3];
            float B0 = ws[OFF_Bc + c * 3];
            ws[OFF_I0 + row + c] = A0 * fabsf(acc[rr][j]) * ix + B0;
        }
    }
}

// ---------------- kernel C: wave-per-batch recurrence, G in VGPRs ----------------
// Lane l: k = l>>5 (stack), m = l&31 (basis coord).
// Register rows: ra=l (rows 0..63), rb=64+l (64..127), rd=144+l (calc 144..207).
// Rows 128..143 (pushfn tail): quad-distributed — lane holds 8 m's of row 128+(l>>2).
__global__ __launch_bounds__(64, 1) void kC(float* __restrict__ ws, const float* __restrict__ sharp) {
    __shared__ float pkL[64];
    __shared__ float nndAll[144];
    __shared__ float nnd2[64];
    const int b = blockIdx.x, l = threadIdx.x;
    const int k = l >> 5, m = l & 31;
    const int rq = 128 + (l >> 2), qq = l & 3;

    // ---- load G rows into registers (coalesced dword loads, one-time) ----
    float Ga[64], Gb[64], Gd[64], Gq[16];
    const float* GI = ws + OFF_GI;
#pragma unroll
    for (int i = 0; i < 32; ++i) {
        Ga[i]      = GI[i * 208 + l];
        Ga[32 + i] = GI[(32 + i) * 208 + l];
        Gb[i]      = GI[i * 208 + 64 + l];
        Gb[32 + i] = GI[(32 + i) * 208 + 64 + l];
        Gd[i]      = GI[i * 208 + 144 + l];
        Gd[32 + i] = GI[(32 + i) * 208 + 144 + l];
    }
#pragma unroll
    for (int j = 0; j < 8; ++j) {
        Gq[2 * j]     = GI[(qq * 8 + j) * 208 + rq];
        Gq[2 * j + 1] = GI[(32 + qq * 8 + j) * 208 + rq];
    }
    float4 Mr[8];
#pragma unroll
    for (int q = 0; q < 8; ++q) Mr[q] = *(const float4*)(ws + OFF_M + m * 32 + q * 4);

    float A1a = ws[OFF_A + l * 3 + 1],        A2a = ws[OFF_A + l * 3 + 2];
    float B1a = ws[OFF_Bc + l * 3 + 1],       B2a = ws[OFF_Bc + l * 3 + 2];
    float A1b = ws[OFF_A + (64 + l) * 3 + 1], A2b = ws[OFF_A + (64 + l) * 3 + 2];
    float B1b = ws[OFF_Bc + (64 + l) * 3 + 1],B2b = ws[OFF_Bc + (64 + l) * 3 + 2];
    float A1q = ws[OFF_A + rq * 3 + 1],       A2q = ws[OFF_A + rq * 3 + 2];
    float B1q = ws[OFF_Bc + rq * 3 + 1],      B2q = ws[OFF_Bc + rq * 3 + 2];
    float A1d = ws[OFF_A + (144 + l) * 3 + 1],A2d = ws[OFF_A + (144 + l) * 3 + 2];
    float B1d = ws[OFF_Bc + (144 + l) * 3 + 1],B2d = ws[OFF_Bc + (144 + l) * 3 + 2];
    const float sh = sharp[k];

    float st[4], p[4];
#pragma unroll
    for (int d = 0; d < 4; ++d) {
        st[d] = (d == 1) ? ((m == 1) ? 1.f : 0.f) : ((m == 0) ? ZOFF : 0.f);
        p[d] = (d == 1) ? 1.f : 0.f;
    }
    const float* i0base = ws + OFF_I0 + (size_t)b * SS * 208;
    float i0a = i0base[l], i0b = i0base[64 + l], i0q = i0base[rq], i0d = i0base[144 + l];
    __syncthreads();

    for (int t = 0; t < SS; ++t) {
        // prefetch next step's i0 (consumed at t+1; overlaps whole step)
        const float* nb = i0base + (size_t)((t < SS - 1) ? (t + 1) : t) * 208;
        float i0na = nb[l], i0nb = nb[64 + l], i0nq = nb[rq], i0nd = nb[144 + l];

        // ---- phase 1: peek, broadcast ----
        float pk = st[0] * p[0] + st[1] * p[1] + st[2] * p[2] + st[3] * p[3];
        pkL[l] = pk;
        __syncthreads();
        float4 P0[8], P1[8];
#pragma unroll
        for (int q = 0; q < 8; ++q) {
            P0[q] = *(const float4*)(pkL + 4 * q);
            P1[q] = *(const float4*)(pkL + 32 + 4 * q);
        }
        float4 u0 = *(const float4*)(pkL + qq * 8);
        float4 u1 = *(const float4*)(pkL + qq * 8 + 4);
        float4 v0 = *(const float4*)(pkL + 32 + qq * 8);
        float4 v1 = *(const float4*)(pkL + 32 + qq * 8 + 4);

        // Gram norms (both stacks; select own)
        float Mv0 = 0.f, Mv1 = 0.f;
#pragma unroll
        for (int q = 0; q < 8; ++q) {
            float4 mr = Mr[q], a = P0[q], c = P1[q];
            Mv0 += mr.x * a.x + mr.y * a.y + mr.z * a.z + mr.w * a.w;
            Mv1 += mr.x * c.x + mr.y * c.y + mr.z * c.z + mr.w * c.w;
        }
        float part = pk * (k ? Mv1 : Mv0);
        part += __shfl_xor(part, 1);  part += __shfl_xor(part, 2);
        part += __shfl_xor(part, 4);  part += __shfl_xor(part, 8);
        part += __shfl_xor(part, 16);
        float qOther = __shfl_xor(part, 32);
        float q0 = k ? qOther : part, q1 = k ? part : qOther;
        float iq0 = 1.f / fmaxf(sqrtf(q0), 1e-8f);
        float iq1 = 1.f / fmaxf(sqrtf(q1), 1e-8f);

        // NAND dots from registers
        float da1 = 0.f, da2 = 0.f, db1 = 0.f, db2 = 0.f;
#pragma unroll
        for (int q = 0; q < 8; ++q) {
            float4 a = P0[q], c = P1[q];
            da1 += a.x * Ga[4*q] + a.y * Ga[4*q+1] + a.z * Ga[4*q+2] + a.w * Ga[4*q+3];
            da2 += c.x * Ga[32+4*q] + c.y * Ga[33+4*q] + c.z * Ga[34+4*q] + c.w * Ga[35+4*q];
            db1 += a.x * Gb[4*q] + a.y * Gb[4*q+1] + a.z * Gb[4*q+2] + a.w * Gb[4*q+3];
            db2 += c.x * Gb[32+4*q] + c.y * Gb[33+4*q] + c.z * Gb[34+4*q] + c.w * Gb[35+4*q];
        }
        float dq1 = u0.x*Gq[0] + u0.y*Gq[2] + u0.z*Gq[4] + u0.w*Gq[6]
                  + u1.x*Gq[8] + u1.y*Gq[10] + u1.z*Gq[12] + u1.w*Gq[14];
        float dq2 = v0.x*Gq[1] + v0.y*Gq[3] + v0.z*Gq[5] + v0.w*Gq[7]
                  + v1.x*Gq[9] + v1.y*Gq[11] + v1.z*Gq[13] + v1.w*Gq[15];
        dq1 += __shfl_xor(dq1, 1); dq1 += __shfl_xor(dq1, 2);
        dq2 += __shfl_xor(dq2, 1); dq2 += __shfl_xor(dq2, 2);

        float nva = i0a * (A1a * fabsf(da1) * iq0 + B1a) * (A2a * fabsf(da2) * iq1 + B2a);
        float nvb = i0b * (A1b * fabsf(db1) * iq0 + B1b) * (A2b * fabsf(db2) * iq1 + B2b);
        float nvq = i0q * (A1q * fabsf(dq1) * iq0 + B1q) * (A2q * fabsf(dq2) * iq1 + B2q);
        nndAll[l] = nva;
        nndAll[64 + l] = nvb;
        if (qq == 0) nndAll[128 + (l >> 2)] = nvq;
        __syncthreads();

        // gates + push_val
        float4 gp4 = *(const float4*)(nndAll + 4 * k);
        float4 gq4 = *(const float4*)(nndAll + 8 + 4 * k);
        float prp0 = 1.f / (1.f + __expf((fmaxf(gp4.z, gp4.w) - fmaxf(gp4.x, gp4.y)) * sh));
        float prq0 = 1.f / (1.f + __expf((fmaxf(gq4.z, gq4.w) - fmaxf(gq4.x, gq4.y)) * sh));
        float prp1 = 1.f - prp0, prq1 = 1.f - prq0;
        float prx = 0.f, pry = 0.f;
        if (m >= 2) {
            float2 pr2 = *(const float2*)(nndAll + 16 + 64 * k + 2 * m - 4);
            prx = pr2.x; pry = pr2.y;
        }
        float4 t30 = *(const float4*)(nndAll + 16 + 64 * k + 60);
        float pkOther = __shfl_xor(pk, 32);
        float pk0m = k ? pkOther : pk;
        float pk1m = k ? pk : pkOther;
        float pvc = prx + pry + (t30.x + t30.y) * pk0m + (t30.z + t30.w) * pk1m;

        // stack update (register-local)
        float zc = (m == 0) ? ZOFF : 0.f;
        float s1[4], p1[4];
#pragma unroll
        for (int d = 0; d < 4; ++d) {
            float ps = st[d] * (1.f - p[d]) + zc * p[d];
            s1[d] = ps * prp0 + st[d] * prp1;
            p1[d] = p[(d + 1) & 3] * prp0 + p[d] * prp1;
        }
        float pn_[4];
#pragma unroll
        for (int d = 0; d < 4; ++d) {
            float pu = p1[(d + 3) & 3];
            float su = s1[d] * (1.f - pu) + pvc * pu;
            st[d] = su * prq0 + s1[d] * prq1;
            pn_[d] = pu * prq0 + p1[d] * prq1;
        }
#pragma unroll
        for (int d = 0; d < 4; ++d) p[d] = pn_[d];

        // ---- phase 2 ----
        float pk2 = st[0] * p[0] + st[1] * p[1] + st[2] * p[2] + st[3] * p[3];
        pkL[l] = pk2;
        __syncthreads();
#pragma unroll
        for (int q = 0; q < 8; ++q) {
            P0[q] = *(const float4*)(pkL + 4 * q);
            P1[q] = *(const float4*)(pkL + 32 + 4 * q);
        }
        Mv0 = 0.f; Mv1 = 0.f;
#pragma unroll
        for (int q = 0; q < 8; ++q) {
            float4 mr = Mr[q], a = P0[q], c = P1[q];
            Mv0 += mr.x * a.x + mr.y * a.y + mr.z * a.z + mr.w * a.w;
            Mv1 += mr.x * c.x + mr.y * c.y + mr.z * c.z + mr.w * c.w;
        }
        part = pk2 * (k ? Mv1 : Mv0);
        part += __shfl_xor(part, 1);  part += __shfl_xor(part, 2);
        part += __shfl_xor(part, 4);  part += __shfl_xor(part, 8);
        part += __shfl_xor(part, 16);
        qOther = __shfl_xor(part, 32);
        q0 = k ? qOther : part; q1 = k ? part : qOther;
        iq0 = 1.f / fmaxf(sqrtf(q0), 1e-8f);
        iq1 = 1.f / fmaxf(sqrtf(q1), 1e-8f);

        float dd1 = 0.f, dd2 = 0.f;
#pragma unroll
        for (int q = 0; q < 8; ++q) {
            float4 a = P0[q], c = P1[q];
            dd1 += a.x * Gd[4*q] + a.y * Gd[4*q+1] + a.z * Gd[4*q+2] + a.w * Gd[4*q+3];
            dd2 += c.x * Gd[32+4*q] + c.y * Gd[33+4*q] + c.z * Gd[34+4*q] + c.w * Gd[35+4*q];
        }
        nnd2[l] = i0d * (A1d * fabsf(dd1) * iq0 + B1d) * (A2d * fabsf(dd2) * iq1 + B2d);
        __syncthreads();

        float cx = 0.f, cy = 0.f;
        if (m >= 2) {
            float2 c2 = *(const float2*)(nnd2 + 2 * m - 4);
            cx = c2.x; cy = c2.y;
        }
        float4 c30 = *(const float4*)(nnd2 + 60);
        float pk2Other = __shfl_xor(pk2, 32);
        float pk0m2 = k ? pk2Other : pk2;
        float pk1m2 = k ? pk2 : pk2Other;
        float oc = cx + cy + (c30.x + c30.y) * pk0m2 + (c30.z + c30.w) * pk1m2;
        if (l < 32) ws[OFF_OC + ((size_t)b * SS + t) * 32 + m] = oc;

        i0a = i0na; i0b = i0nb; i0q = i0nq; i0d = i0nd;
        __syncthreads();
    }
}

// ---------------- kernel D: expand coords -> 512-dim output (barrier-free) ----------------
__global__ __launch_bounds__(256) void kD(const float* __restrict__ ws, const float* __restrict__ syms,
                                          const float* __restrict__ siv, float* __restrict__ out) {
    int t = threadIdx.x;
    int rg = t >> 6;
    int vc = (t & 63) * 8;
    size_t r0 = (size_t)blockIdx.x * 16 + rg * 4;
    const float* oc = ws + OFF_OC;
    float acc[4][8];
    float4 sv0 = *(const float4*)(siv + vc);
    float4 sv1 = *(const float4*)(siv + vc + 4);
#pragma unroll
    for (int rr = 0; rr < 4; ++rr) {
        float c0 = oc[(r0 + rr) * 32 + 0];
        float c1 = oc[(r0 + rr) * 32 + 1];
        acc[rr][0] = c0 + c1 * sv0.x; acc[rr][1] = c0 + c1 * sv0.y;
        acc[rr][2] = c0 + c1 * sv0.z; acc[rr][3] = c0 + c1 * sv0.w;
        acc[rr][4] = c0 + c1 * sv1.x; acc[rr][5] = c0 + c1 * sv1.y;
        acc[rr][6] = c0 + c1 * sv1.z; acc[rr][7] = c0 + c1 * sv1.w;
    }
    for (int mm = 0; mm < 30; ++mm) {
        float4 b0 = *(const float4*)(syms + mm * 512 + vc);
        float4 b1 = *(const float4*)(syms + mm * 512 + vc + 4);
#pragma unroll
        for (int rr = 0; rr < 4; ++rr) {
            float c = oc[(r0 + rr) * 32 + 2 + mm];
            acc[rr][0] += c * b0.x; acc[rr][1] += c * b0.y;
            acc[rr][2] += c * b0.z; acc[rr][3] += c * b0.w;
            acc[rr][4] += c * b1.x; acc[rr][5] += c * b1.y;
            acc[rr][6] += c * b1.z; acc[rr][7] += c * b1.w;
        }
    }
#pragma unroll
    for (int rr = 0; rr < 4; ++rr) {
        float* o = out + (r0 + rr) * 512 + vc;
        *(float4*)o       = make_float4(acc[rr][0], acc[rr][1], acc[rr][2], acc[rr][3]);
        *(float4*)(o + 4) = make_float4(acc[rr][4], acc[rr][5], acc[rr][6], acc[rr][7]);
    }
}

extern "C" void kernel_launch(void* const* d_in, const int* in_sizes, int n_in,
                              void* d_out, int out_size, void* d_ws, size_t ws_size,
                              hipStream_t stream) {
    const float* x    = (const float*)d_in[0];
    const float* syms = (const float*)d_in[1];
    const float* siv  = (const float*)d_in[2];
    const float* shp  = (const float*)d_in[3];
    const float* pw   = (const float*)d_in[4];
    const float* pn   = (const float*)d_in[5];
    const float* pow_ = (const float*)d_in[6];
    const float* pon  = (const float*)d_in[7];
    const float* pfw  = (const float*)d_in[8];
    const float* pfn  = (const float*)d_in[9];
    const float* cw   = (const float*)d_in[10];
    const float* cn   = (const float*)d_in[11];
    float* ws  = (float*)d_ws;
    float* out = (float*)d_out;

    hipLaunchKernelGGL(kB, dim3(82),   dim3(256), 0, stream,
                       syms, siv, pw, pn, pow_, pon, pfw, pfn, cw, cn, ws);
    hipLaunchKernelGGL(kA, dim3(512),  dim3(256), 0, stream, x, ws);
    hipLaunchKernelGGL(kC, dim3(256),  dim3(64),  0, stream, ws, shp);
    hipLaunchKernelGGL(kD, dim3(2048), dim3(256), 0, stream, ws, syms, siv, out);
}

// Round 5
// 702.108 us; speedup vs baseline: 2.1603x; 1.0046x over previous
//
#include <hip/hip_runtime.h>
#include <math.h>

// Cyborg stack machine: B=256, S=128, V=512, H=30, N_STACKS=2, R=2, DEPTH=4
// All stack/peek/output vectors live in span{ones, init_vec, syms0..29} (32-dim).
// kC: one wave per batch chain; G table entirely in VGPRs. amdgpu_waves_per_eu(1,1)
// forces the ~512-VGPR budget (R4 lesson: launch_bounds(64,1) alone capped at 188
// VGPRs and spilled the 208-float G arrays to scratch — the whole bottleneck).

#define SS 128
#define VV 512
#define NROWS 208      // 8 pop + 8 pushop + 128 pushfn + 64 calc
#define ZOFF 1e-6f

// ws layout (float offsets)
#define OFF_I0   0                          // interp0: 32768*208
#define OFF_OC   (32768*208)                // out coords: 32768*32
#define OFF_GI   (OFF_OC + 32768*32)        // G[2][32][208]  (stack, basis, row)
#define OFF_M    (OFF_GI + 2*32*208)        // Gram 32*32
#define OFF_A    (OFF_M + 1024)             // A coef 208*3
#define OFF_Bc   (OFF_A + 624)              // B coef 208*3
#define OFF_W0   (OFF_Bc + 624)             // gathered w j=0 slice [208][512]

__device__ __forceinline__ const float* w_row(int r, const float* pw, const float* pow_,
                                              const float* pfw, const float* cw) {
    if (r < 8)   return pw   + r * 1536;
    if (r < 16)  return pow_ + (r - 8) * 1536;
    if (r < 144) return pfw  + (r - 16) * 1536;
    return cw + (r - 144) * 1536;
}
__device__ __forceinline__ const float* nw_row(int r, const float* pn, const float* pon,
                                               const float* pfn, const float* cn) {
    if (r < 8)   return pn   + r * 3;
    if (r < 16)  return pon  + (r - 8) * 3;
    if (r < 144) return pfn  + (r - 16) * 3;
    return cn + (r - 144) * 3;
}

// ---------------- kernel B: precompute tables ----------------
__global__ void kB(const float* __restrict__ syms, const float* __restrict__ siv,
                   const float* __restrict__ pw, const float* __restrict__ pn,
                   const float* __restrict__ pow_, const float* __restrict__ pon,
                   const float* __restrict__ pfw, const float* __restrict__ pfn,
                   const float* __restrict__ cw, const float* __restrict__ cn,
                   float* __restrict__ ws) {
    int blk = blockIdx.x, tid = threadIdx.x;
    if (blk < 64) {
        // G[jj][e][c] = basis_e . w_row(c)[(jj+1)*512 ..)
        int jj = blk >> 5, e = blk & 31;
        __shared__ float bas[512];
        for (int i = tid; i < 512; i += 256)
            bas[i] = (e == 0) ? 1.0f : ((e == 1) ? siv[i] : syms[(e - 2) * 512 + i]);
        __syncthreads();
        if (tid < NROWS) {
            int c = tid;
            const float4* w4 = (const float4*)(w_row(c, pw, pow_, pfw, cw) + (jj + 1) * 512);
            const float4* b4 = (const float4*)bas;
            float s = 0.f;
            for (int q = 0; q < 128; ++q) {
                float4 a = b4[q], b = w4[q];
                s += a.x * b.x + a.y * b.y + a.z * b.z + a.w * b.w;
            }
            ws[OFF_GI + (jj * 32 + e) * 208 + c] = s;
        }
    } else if (blk == 64) {
        // Gram M[m][mm]
        __shared__ float basw[32 * 512];
        for (int i = tid; i < 32 * 512; i += 256) {
            int m = i >> 9, v = i & 511;
            basw[i] = (m == 0) ? 1.0f : ((m == 1) ? siv[v] : syms[(m - 2) * 512 + v]);
        }
        __syncthreads();
        for (int p = tid; p < 1024; p += 256) {
            int m = p >> 5, mm = p & 31;
            const float4* a4 = (const float4*)(basw + m * 512);
            const float4* b4 = (const float4*)(basw + mm * 512);
            float s = 0.f;
            for (int q = 0; q < 128; ++q) {
                float4 a = a4[q], b = b4[q];
                s += a.x * b.x + a.y * b.y + a.z * b.z + a.w * b.w;
            }
            ws[OFF_M + p] = s;
        }
    } else if (blk == 65) {
        // folded NAND coefs: A=(2*sig-1)/||w||, B=1-sig   for (r, j)
        for (int idx = tid; idx < 624; idx += 256) {
            int r = idx / 3, j = idx % 3;
            const float4* w4 = (const float4*)(w_row(r, pw, pow_, pfw, cw) + j * 512);
            float s = 0.f;
            for (int q = 0; q < 128; ++q) {
                float4 b = w4[q];
                s += b.x * b.x + b.y * b.y + b.z * b.z + b.w * b.w;
            }
            float nrm = fmaxf(sqrtf(s), 1e-8f);
            float nwv = nw_row(r, pn, pon, pfn, cn)[j];
            float sig = 1.f / (1.f + expf(-nwv));
            ws[OFF_A + idx]  = (2.f * sig - 1.f) / nrm;
            ws[OFF_Bc + idx] = 1.f - sig;
        }
    } else {
        // gather w j=0 slice into contiguous [208][512] — 16 blocks
        int part = blk - 66;
        for (int i = tid; i < 6656; i += 256) {
            int flat = part * 6656 + i;
            int c = flat >> 9, v = flat & 511;
            ws[OFF_W0 + flat] = w_row(c, pw, pow_, pfw, cw)[v];
        }
    }
}

// ---------------- kernel A: interp0 via LDS-tiled f32 GEMM ----------------
__global__ __launch_bounds__(256) void kA(const float* __restrict__ x, float* __restrict__ ws) {
    __shared__ float xs[64 * 36];
    __shared__ float wsh[208 * 36];
    __shared__ float red[256];
    __shared__ float invx[64];
    int blk = blockIdx.x, tid = threadIdx.x;
    size_t bt0 = (size_t)blk * 64;

    {
        int r = tid >> 2, seg = tid & 3;
        const float4* xr = (const float4*)(x + (bt0 + r) * 512 + seg * 128);
        float s = 0.f;
        for (int q = 0; q < 32; ++q) {
            float4 a = xr[q];
            s += a.x * a.x + a.y * a.y + a.z * a.z + a.w * a.w;
        }
        red[tid] = s;
    }
    __syncthreads();
    if (tid < 64) {
        float s = red[tid * 4] + red[tid * 4 + 1] + red[tid * 4 + 2] + red[tid * 4 + 3];
        invx[tid] = 1.f / fmaxf(sqrtf(s), 1e-8f);
    }

    int tx = tid & 15, ty = tid >> 4;
    float acc[4][13];
    for (int rr = 0; rr < 4; ++rr)
        for (int j = 0; j < 13; ++j) acc[rr][j] = 0.f;

    const float* w0 = ws + OFF_W0;
    for (int kt = 0; kt < 16; ++kt) {
        __syncthreads();
        for (int it = 0; it < 8; ++it) {
            int i = tid + 256 * it;
            int r = i >> 5, kk = i & 31;
            xs[r * 36 + kk] = x[(bt0 + r) * 512 + kt * 32 + kk];
        }
        for (int i = tid; i < 6656; i += 256) {
            int c = i >> 5, kk = i & 31;
            wsh[c * 36 + kk] = w0[c * 512 + kt * 32 + kk];
        }
        __syncthreads();
        for (int g = 0; g < 8; ++g) {
            int k = g * 4;
            float4 a4[4], b4[13];
            for (int rr = 0; rr < 4; ++rr)
                a4[rr] = *(const float4*)(xs + (ty * 4 + rr) * 36 + k);
            for (int j = 0; j < 13; ++j)
                b4[j] = *(const float4*)(wsh + (tx + 16 * j) * 36 + k);
            for (int rr = 0; rr < 4; ++rr)
                for (int j = 0; j < 13; ++j) {
                    float4 a = a4[rr], b = b4[j];
                    acc[rr][j] += a.x * b.x + a.y * b.y + a.z * b.z + a.w * b.w;
                }
        }
    }
    for (int rr = 0; rr < 4; ++rr) {
        int r = ty * 4 + rr;
        float ix = invx[r];
        size_t row = (bt0 + r) * 208;
        for (int j = 0; j < 13; ++j) {
            int c = tx + 16 * j;
            float A0 = ws[OFF_A + c * 3];
            float B0 = ws[OFF_Bc + c * 3];
            ws[OFF_I0 + row + c] = A0 * fabsf(acc[rr][j]) * ix + B0;
        }
    }
}

// ---------------- kernel C: wave-per-batch recurrence, G in VGPRs ----------------
// Lane l: k = l>>5 (stack), m = l&31 (basis coord).
// Register rows: ra=l (rows 0..63), rb=64+l (64..127), rd=144+l (calc 144..207).
// Rows 128..143 (pushfn tail): quad-distributed — lane holds 8 m's of row 128+(l>>2).
__global__ __attribute__((amdgpu_flat_work_group_size(64, 64), amdgpu_waves_per_eu(1, 1)))
void kC(float* __restrict__ ws, const float* __restrict__ sharp) {
    __shared__ float pkL[64];
    __shared__ float nndAll[144];
    __shared__ float nnd2[64];
    const int b = blockIdx.x, l = threadIdx.x;
    const int k = l >> 5, m = l & 31;
    const int rq = 128 + (l >> 2), qq = l & 3;

    // ---- load G rows into registers (coalesced dword loads, one-time) ----
    float Ga[64], Gb[64], Gd[64], Gq[16];
    const float* GI = ws + OFF_GI;
#pragma unroll
    for (int i = 0; i < 32; ++i) {
        Ga[i]      = GI[i * 208 + l];
        Ga[32 + i] = GI[(32 + i) * 208 + l];
        Gb[i]      = GI[i * 208 + 64 + l];
        Gb[32 + i] = GI[(32 + i) * 208 + 64 + l];
        Gd[i]      = GI[i * 208 + 144 + l];
        Gd[32 + i] = GI[(32 + i) * 208 + 144 + l];
    }
#pragma unroll
    for (int j = 0; j < 8; ++j) {
        Gq[2 * j]     = GI[(qq * 8 + j) * 208 + rq];
        Gq[2 * j + 1] = GI[(32 + qq * 8 + j) * 208 + rq];
    }
    float4 Mr[8];
#pragma unroll
    for (int q = 0; q < 8; ++q) Mr[q] = *(const float4*)(ws + OFF_M + m * 32 + q * 4);

    float A1a = ws[OFF_A + l * 3 + 1],        A2a = ws[OFF_A + l * 3 + 2];
    float B1a = ws[OFF_Bc + l * 3 + 1],       B2a = ws[OFF_Bc + l * 3 + 2];
    float A1b = ws[OFF_A + (64 + l) * 3 + 1], A2b = ws[OFF_A + (64 + l) * 3 + 2];
    float B1b = ws[OFF_Bc + (64 + l) * 3 + 1],B2b = ws[OFF_Bc + (64 + l) * 3 + 2];
    float A1q = ws[OFF_A + rq * 3 + 1],       A2q = ws[OFF_A + rq * 3 + 2];
    float B1q = ws[OFF_Bc + rq * 3 + 1],      B2q = ws[OFF_Bc + rq * 3 + 2];
    float A1d = ws[OFF_A + (144 + l) * 3 + 1],A2d = ws[OFF_A + (144 + l) * 3 + 2];
    float B1d = ws[OFF_Bc + (144 + l) * 3 + 1],B2d = ws[OFF_Bc + (144 + l) * 3 + 2];
    const float sh = sharp[k];

    float st[4], p[4];
#pragma unroll
    for (int d = 0; d < 4; ++d) {
        st[d] = (d == 1) ? ((m == 1) ? 1.f : 0.f) : ((m == 0) ? ZOFF : 0.f);
        p[d] = (d == 1) ? 1.f : 0.f;
    }
    const float* i0base = ws + OFF_I0 + (size_t)b * SS * 208;
    float i0a = i0base[l], i0b = i0base[64 + l], i0q = i0base[rq], i0d = i0base[144 + l];
    __syncthreads();

    for (int t = 0; t < SS; ++t) {
        // prefetch next step's i0 (consumed at t+1; overlaps whole step)
        const float* nb = i0base + (size_t)((t < SS - 1) ? (t + 1) : t) * 208;
        float i0na = nb[l], i0nb = nb[64 + l], i0nq = nb[rq], i0nd = nb[144 + l];

        // ---- phase 1: peek, broadcast ----
        float pk = st[0] * p[0] + st[1] * p[1] + st[2] * p[2] + st[3] * p[3];
        pkL[l] = pk;
        __syncthreads();
        float4 P0[8], P1[8];
#pragma unroll
        for (int q = 0; q < 8; ++q) {
            P0[q] = *(const float4*)(pkL + 4 * q);
            P1[q] = *(const float4*)(pkL + 32 + 4 * q);
        }
        float4 u0 = *(const float4*)(pkL + qq * 8);
        float4 u1 = *(const float4*)(pkL + qq * 8 + 4);
        float4 v0 = *(const float4*)(pkL + 32 + qq * 8);
        float4 v1 = *(const float4*)(pkL + 32 + qq * 8 + 4);

        // Gram norms (both stacks; select own)
        float Mv0 = 0.f, Mv1 = 0.f;
#pragma unroll
        for (int q = 0; q < 8; ++q) {
            float4 mr = Mr[q], a = P0[q], c = P1[q];
            Mv0 += mr.x * a.x + mr.y * a.y + mr.z * a.z + mr.w * a.w;
            Mv1 += mr.x * c.x + mr.y * c.y + mr.z * c.z + mr.w * c.w;
        }
        float part = pk * (k ? Mv1 : Mv0);
        part += __shfl_xor(part, 1);  part += __shfl_xor(part, 2);
        part += __shfl_xor(part, 4);  part += __shfl_xor(part, 8);
        part += __shfl_xor(part, 16);
        float qOther = __shfl_xor(part, 32);
        float q0 = k ? qOther : part, q1 = k ? part : qOther;
        float iq0 = 1.f / fmaxf(sqrtf(q0), 1e-8f);
        float iq1 = 1.f / fmaxf(sqrtf(q1), 1e-8f);

        // NAND dots from registers
        float da1 = 0.f, da2 = 0.f, db1 = 0.f, db2 = 0.f;
#pragma unroll
        for (int q = 0; q < 8; ++q) {
            float4 a = P0[q], c = P1[q];
            da1 += a.x * Ga[4*q] + a.y * Ga[4*q+1] + a.z * Ga[4*q+2] + a.w * Ga[4*q+3];
            da2 += c.x * Ga[32+4*q] + c.y * Ga[33+4*q] + c.z * Ga[34+4*q] + c.w * Ga[35+4*q];
            db1 += a.x * Gb[4*q] + a.y * Gb[4*q+1] + a.z * Gb[4*q+2] + a.w * Gb[4*q+3];
            db2 += c.x * Gb[32+4*q] + c.y * Gb[33+4*q] + c.z * Gb[34+4*q] + c.w * Gb[35+4*q];
        }
        float dq1 = u0.x*Gq[0] + u0.y*Gq[2] + u0.z*Gq[4] + u0.w*Gq[6]
                  + u1.x*Gq[8] + u1.y*Gq[10] + u1.z*Gq[12] + u1.w*Gq[14];
        float dq2 = v0.x*Gq[1] + v0.y*Gq[3] + v0.z*Gq[5] + v0.w*Gq[7]
                  + v1.x*Gq[9] + v1.y*Gq[11] + v1.z*Gq[13] + v1.w*Gq[15];
        dq1 += __shfl_xor(dq1, 1); dq1 += __shfl_xor(dq1, 2);
        dq2 += __shfl_xor(dq2, 1); dq2 += __shfl_xor(dq2, 2);

        float nva = i0a * (A1a * fabsf(da1) * iq0 + B1a) * (A2a * fabsf(da2) * iq1 + B2a);
        float nvb = i0b * (A1b * fabsf(db1) * iq0 + B1b) * (A2b * fabsf(db2) * iq1 + B2b);
        float nvq = i0q * (A1q * fabsf(dq1) * iq0 + B1q) * (A2q * fabsf(dq2) * iq1 + B2q);
        nndAll[l] = nva;
        nndAll[64 + l] = nvb;
        if (qq == 0) nndAll[128 + (l >> 2)] = nvq;
        __syncthreads();

        // gates + push_val
        float4 gp4 = *(const float4*)(nndAll + 4 * k);
        float4 gq4 = *(const float4*)(nndAll + 8 + 4 * k);
        float prp0 = 1.f / (1.f + __expf((fmaxf(gp4.z, gp4.w) - fmaxf(gp4.x, gp4.y)) * sh));
        float prq0 = 1.f / (1.f + __expf((fmaxf(gq4.z, gq4.w) - fmaxf(gq4.x, gq4.y)) * sh));
        float prp1 = 1.f - prp0, prq1 = 1.f - prq0;
        float prx = 0.f, pry = 0.f;
        if (m >= 2) {
            float2 pr2 = *(const float2*)(nndAll + 16 + 64 * k + 2 * m - 4);
            prx = pr2.x; pry = pr2.y;
        }
        float4 t30 = *(const float4*)(nndAll + 16 + 64 * k + 60);
        float pkOther = __shfl_xor(pk, 32);
        float pk0m = k ? pkOther : pk;
        float pk1m = k ? pk : pkOther;
        float pvc = prx + pry + (t30.x + t30.y) * pk0m + (t30.z + t30.w) * pk1m;

        // stack update (register-local)
        float zc = (m == 0) ? ZOFF : 0.f;
        float s1[4], p1[4];
#pragma unroll
        for (int d = 0; d < 4; ++d) {
            float ps = st[d] * (1.f - p[d]) + zc * p[d];
            s1[d] = ps * prp0 + st[d] * prp1;
            p1[d] = p[(d + 1) & 3] * prp0 + p[d] * prp1;
        }
        float pn_[4];
#pragma unroll
        for (int d = 0; d < 4; ++d) {
            float pu = p1[(d + 3) & 3];
            float su = s1[d] * (1.f - pu) + pvc * pu;
            st[d] = su * prq0 + s1[d] * prq1;
            pn_[d] = pu * prq0 + p1[d] * prq1;
        }
#pragma unroll
        for (int d = 0; d < 4; ++d) p[d] = pn_[d];

        // ---- phase 2 ----
        float pk2 = st[0] * p[0] + st[1] * p[1] + st[2] * p[2] + st[3] * p[3];
        pkL[l] = pk2;
        __syncthreads();
#pragma unroll
        for (int q = 0; q < 8; ++q) {
            P0[q] = *(const float4*)(pkL + 4 * q);
            P1[q] = *(const float4*)(pkL + 32 + 4 * q);
        }
        Mv0 = 0.f; Mv1 = 0.f;
#pragma unroll
        for (int q = 0; q < 8; ++q) {
            float4 mr = Mr[q], a = P0[q], c = P1[q];
            Mv0 += mr.x * a.x + mr.y * a.y + mr.z * a.z + mr.w * a.w;
            Mv1 += mr.x * c.x + mr.y * c.y + mr.z * c.z + mr.w * c.w;
        }
        part = pk2 * (k ? Mv1 : Mv0);
        part += __shfl_xor(part, 1);  part += __shfl_xor(part, 2);
        part += __shfl_xor(part, 4);  part += __shfl_xor(part, 8);
        part += __shfl_xor(part, 16);
        qOther = __shfl_xor(part, 32);
        q0 = k ? qOther : part; q1 = k ? part : qOther;
        iq0 = 1.f / fmaxf(sqrtf(q0), 1e-8f);
        iq1 = 1.f / fmaxf(sqrtf(q1), 1e-8f);

        float dd1 = 0.f, dd2 = 0.f;
#pragma unroll
        for (int q = 0; q < 8; ++q) {
            float4 a = P0[q], c = P1[q];
            dd1 += a.x * Gd[4*q] + a.y * Gd[4*q+1] + a.z * Gd[4*q+2] + a.w * Gd[4*q+3];
            dd2 += c.x * Gd[32+4*q] + c.y * Gd[33+4*q] + c.z * Gd[34+4*q] + c.w * Gd[35+4*q];
        }
        nnd2[l] = i0d * (A1d * fabsf(dd1) * iq0 + B1d) * (A2d * fabsf(dd2) * iq1 + B2d);
        __syncthreads();

        float cx = 0.f, cy = 0.f;
        if (m >= 2) {
            float2 c2 = *(const float2*)(nnd2 + 2 * m - 4);
            cx = c2.x; cy = c2.y;
        }
        float4 c30 = *(const float4*)(nnd2 + 60);
        float pk2Other = __shfl_xor(pk2, 32);
        float pk0m2 = k ? pk2Other : pk2;
        float pk1m2 = k ? pk2 : pk2Other;
        float oc = cx + cy + (c30.x + c30.y) * pk0m2 + (c30.z + c30.w) * pk1m2;
        if (l < 32) ws[OFF_OC + ((size_t)b * SS + t) * 32 + m] = oc;

        i0a = i0na; i0b = i0nb; i0q = i0nq; i0d = i0nd;
        __syncthreads();
    }
}

// ---------------- kernel D: expand coords -> 512-dim output (barrier-free) ----------------
__global__ __launch_bounds__(256) void kD(const float* __restrict__ ws, const float* __restrict__ syms,
                                          const float* __restrict__ siv, float* __restrict__ out) {
    int t = threadIdx.x;
    int rg = t >> 6;
    int vc = (t & 63) * 8;
    size_t r0 = (size_t)blockIdx.x * 16 + rg * 4;
    const float* oc = ws + OFF_OC;
    float acc[4][8];
    float4 sv0 = *(const float4*)(siv + vc);
    float4 sv1 = *(const float4*)(siv + vc + 4);
#pragma unroll
    for (int rr = 0; rr < 4; ++rr) {
        float c0 = oc[(r0 + rr) * 32 + 0];
        float c1 = oc[(r0 + rr) * 32 + 1];
        acc[rr][0] = c0 + c1 * sv0.x; acc[rr][1] = c0 + c1 * sv0.y;
        acc[rr][2] = c0 + c1 * sv0.z; acc[rr][3] = c0 + c1 * sv0.w;
        acc[rr][4] = c0 + c1 * sv1.x; acc[rr][5] = c0 + c1 * sv1.y;
        acc[rr][6] = c0 + c1 * sv1.z; acc[rr][7] = c0 + c1 * sv1.w;
    }
    for (int mm = 0; mm < 30; ++mm) {
        float4 b0 = *(const float4*)(syms + mm * 512 + vc);
        float4 b1 = *(const float4*)(syms + mm * 512 + vc + 4);
#pragma unroll
        for (int rr = 0; rr < 4; ++rr) {
            float c = oc[(r0 + rr) * 32 + 2 + mm];
            acc[rr][0] += c * b0.x; acc[rr][1] += c * b0.y;
            acc[rr][2] += c * b0.z; acc[rr][3] += c * b0.w;
            acc[rr][4] += c * b1.x; acc[rr][5] += c * b1.y;
            acc[rr][6] += c * b1.z; acc[rr][7] += c * b1.w;
        }
    }
#pragma unroll
    for (int rr = 0; rr < 4; ++rr) {
        float* o = out + (r0 + rr) * 512 + vc;
        *(float4*)o       = make_float4(acc[rr][0], acc[rr][1], acc[rr][2], acc[rr][3]);
        *(float4*)(o + 4) = make_float4(acc[rr][4], acc[rr][5], acc[rr][6], acc[rr][7]);
    }
}

extern "C" void kernel_launch(void* const* d_in, const int* in_sizes, int n_in,
                              void* d_out, int out_size, void* d_ws, size_t ws_size,
                              hipStream_t stream) {
    const float* x    = (const float*)d_in[0];
    const float* syms = (const float*)d_in[1];
    const float* siv  = (const float*)d_in[2];
    const float* shp  = (const float*)d_in[3];
    const float* pw   = (const float*)d_in[4];
    const float* pn   = (const float*)d_in[5];
    const float* pow_ = (const float*)d_in[6];
    const float* pon  = (const float*)d_in[7];
    const float* pfw  = (const float*)d_in[8];
    const float* pfn  = (const float*)d_in[9];
    const float* cw   = (const float*)d_in[10];
    const float* cn   = (const float*)d_in[11];
    float* ws  = (float*)d_ws;
    float* out = (float*)d_out;

    hipLaunchKernelGGL(kB, dim3(82),   dim3(256), 0, stream,
                       syms, siv, pw, pn, pow_, pon, pfw, pfn, cw, cn, ws);
    hipLaunchKernelGGL(kA, dim3(512),  dim3(256), 0, stream, x, ws);
    hipLaunchKernelGGL(kC, dim3(256),  dim3(64),  0, stream, ws, shp);
    hipLaunchKernelGGL(kD, dim3(2048), dim3(256), 0, stream, ws, syms, siv, out);
}

// Round 6
// 566.006 us; speedup vs baseline: 2.6798x; 1.2405x over previous
//
#include <hip/hip_runtime.h>
#include <math.h>

// Cyborg stack machine: B=256, S=128, V=512, H=30, N_STACKS=2, R=2, DEPTH=4
// All stack/peek/output vectors live in span{ones, init_vec, syms0..29} (32-dim).
// kC (R5 redesign): 4 waves/block, ONE ROW PER THREAD (64 G floats/lane — fits
// under the allocator's 188-VGPR cap, no spills). Stack state replicated in all
// 4 waves; peek/Gram computed once per step (phase-2 peek == next phase-1 peek).
// 4 barriers/step.

#define SS 128
#define VV 512
#define NROWS 208      // 8 pop + 8 pushop + 128 pushfn + 64 calc
#define ZOFF 1e-6f

// ws layout (float offsets)
#define OFF_I0   0                          // interp0: 32768*208
#define OFF_OC   (32768*208)                // out coords: 32768*32
#define OFF_GI   (OFF_OC + 32768*32)        // G[2][32][208]  (stack, basis, row)
#define OFF_M    (OFF_GI + 2*32*208)        // Gram 32*32
#define OFF_A    (OFF_M + 1024)             // A coef 208*3
#define OFF_Bc   (OFF_A + 624)              // B coef 208*3
#define OFF_W0   (OFF_Bc + 624)             // gathered w j=0 slice [208][512]

__device__ __forceinline__ const float* w_row(int r, const float* pw, const float* pow_,
                                              const float* pfw, const float* cw) {
    if (r < 8)   return pw   + r * 1536;
    if (r < 16)  return pow_ + (r - 8) * 1536;
    if (r < 144) return pfw  + (r - 16) * 1536;
    return cw + (r - 144) * 1536;
}
__device__ __forceinline__ const float* nw_row(int r, const float* pn, const float* pon,
                                               const float* pfn, const float* cn) {
    if (r < 8)   return pn   + r * 3;
    if (r < 16)  return pon  + (r - 8) * 3;
    if (r < 144) return pfn  + (r - 16) * 3;
    return cn + (r - 144) * 3;
}

// ---------------- kernel B: precompute tables ----------------
__global__ void kB(const float* __restrict__ syms, const float* __restrict__ siv,
                   const float* __restrict__ pw, const float* __restrict__ pn,
                   const float* __restrict__ pow_, const float* __restrict__ pon,
                   const float* __restrict__ pfw, const float* __restrict__ pfn,
                   const float* __restrict__ cw, const float* __restrict__ cn,
                   float* __restrict__ ws) {
    int blk = blockIdx.x, tid = threadIdx.x;
    if (blk < 64) {
        // G[jj][e][c] = basis_e . w_row(c)[(jj+1)*512 ..)
        int jj = blk >> 5, e = blk & 31;
        __shared__ float bas[512];
        for (int i = tid; i < 512; i += 256)
            bas[i] = (e == 0) ? 1.0f : ((e == 1) ? siv[i] : syms[(e - 2) * 512 + i]);
        __syncthreads();
        if (tid < NROWS) {
            int c = tid;
            const float4* w4 = (const float4*)(w_row(c, pw, pow_, pfw, cw) + (jj + 1) * 512);
            const float4* b4 = (const float4*)bas;
            float s = 0.f;
            for (int q = 0; q < 128; ++q) {
                float4 a = b4[q], b = w4[q];
                s += a.x * b.x + a.y * b.y + a.z * b.z + a.w * b.w;
            }
            ws[OFF_GI + (jj * 32 + e) * 208 + c] = s;
        }
    } else if (blk == 64) {
        // Gram M[m][mm]
        __shared__ float basw[32 * 512];
        for (int i = tid; i < 32 * 512; i += 256) {
            int m = i >> 9, v = i & 511;
            basw[i] = (m == 0) ? 1.0f : ((m == 1) ? siv[v] : syms[(m - 2) * 512 + v]);
        }
        __syncthreads();
        for (int p = tid; p < 1024; p += 256) {
            int m = p >> 5, mm = p & 31;
            const float4* a4 = (const float4*)(basw + m * 512);
            const float4* b4 = (const float4*)(basw + mm * 512);
            float s = 0.f;
            for (int q = 0; q < 128; ++q) {
                float4 a = a4[q], b = b4[q];
                s += a.x * b.x + a.y * b.y + a.z * b.z + a.w * b.w;
            }
            ws[OFF_M + p] = s;
        }
    } else if (blk == 65) {
        // folded NAND coefs: A=(2*sig-1)/||w||, B=1-sig   for (r, j)
        for (int idx = tid; idx < 624; idx += 256) {
            int r = idx / 3, j = idx % 3;
            const float4* w4 = (const float4*)(w_row(r, pw, pow_, pfw, cw) + j * 512);
            float s = 0.f;
            for (int q = 0; q < 128; ++q) {
                float4 b = w4[q];
                s += b.x * b.x + b.y * b.y + b.z * b.z + b.w * b.w;
            }
            float nrm = fmaxf(sqrtf(s), 1e-8f);
            float nwv = nw_row(r, pn, pon, pfn, cn)[j];
            float sig = 1.f / (1.f + expf(-nwv));
            ws[OFF_A + idx]  = (2.f * sig - 1.f) / nrm;
            ws[OFF_Bc + idx] = 1.f - sig;
        }
    } else {
        // gather w j=0 slice into contiguous [208][512] — 16 blocks
        int part = blk - 66;
        for (int i = tid; i < 6656; i += 256) {
            int flat = part * 6656 + i;
            int c = flat >> 9, v = flat & 511;
            ws[OFF_W0 + flat] = w_row(c, pw, pow_, pfw, cw)[v];
        }
    }
}

// ---------------- kernel A: interp0 via LDS-tiled f32 GEMM ----------------
__global__ __launch_bounds__(256) void kA(const float* __restrict__ x, float* __restrict__ ws) {
    __shared__ float xs[64 * 36];
    __shared__ float wsh[208 * 36];
    __shared__ float red[256];
    __shared__ float invx[64];
    int blk = blockIdx.x, tid = threadIdx.x;
    size_t bt0 = (size_t)blk * 64;

    {
        int r = tid >> 2, seg = tid & 3;
        const float4* xr = (const float4*)(x + (bt0 + r) * 512 + seg * 128);
        float s = 0.f;
        for (int q = 0; q < 32; ++q) {
            float4 a = xr[q];
            s += a.x * a.x + a.y * a.y + a.z * a.z + a.w * a.w;
        }
        red[tid] = s;
    }
    __syncthreads();
    if (tid < 64) {
        float s = red[tid * 4] + red[tid * 4 + 1] + red[tid * 4 + 2] + red[tid * 4 + 3];
        invx[tid] = 1.f / fmaxf(sqrtf(s), 1e-8f);
    }

    int tx = tid & 15, ty = tid >> 4;
    float acc[4][13];
    for (int rr = 0; rr < 4; ++rr)
        for (int j = 0; j < 13; ++j) acc[rr][j] = 0.f;

    const float* w0 = ws + OFF_W0;
    for (int kt = 0; kt < 16; ++kt) {
        __syncthreads();
        for (int it = 0; it < 8; ++it) {
            int i = tid + 256 * it;
            int r = i >> 5, kk = i & 31;
            xs[r * 36 + kk] = x[(bt0 + r) * 512 + kt * 32 + kk];
        }
        for (int i = tid; i < 6656; i += 256) {
            int c = i >> 5, kk = i & 31;
            wsh[c * 36 + kk] = w0[c * 512 + kt * 32 + kk];
        }
        __syncthreads();
        for (int g = 0; g < 8; ++g) {
            int k = g * 4;
            float4 a4[4], b4[13];
            for (int rr = 0; rr < 4; ++rr)
                a4[rr] = *(const float4*)(xs + (ty * 4 + rr) * 36 + k);
            for (int j = 0; j < 13; ++j)
                b4[j] = *(const float4*)(wsh + (tx + 16 * j) * 36 + k);
            for (int rr = 0; rr < 4; ++rr)
                for (int j = 0; j < 13; ++j) {
                    float4 a = a4[rr], b = b4[j];
                    acc[rr][j] += a.x * b.x + a.y * b.y + a.z * b.z + a.w * b.w;
                }
        }
    }
    for (int rr = 0; rr < 4; ++rr) {
        int r = ty * 4 + rr;
        float ix = invx[r];
        size_t row = (bt0 + r) * 208;
        for (int j = 0; j < 13; ++j) {
            int c = tx + 16 * j;
            float A0 = ws[OFF_A + c * 3];
            float B0 = ws[OFF_Bc + c * 3];
            ws[OFF_I0 + row + c] = A0 * fabsf(acc[rr][j]) * ix + B0;
        }
    }
}

// ---------------- kernel C: 4 waves/block, one row per thread ----------------
// tid 0..143:   phase-1 row tid (G1[64] in regs)
// wave3 (192..255): calc row 144+(tid&63) (G2[64])
// wave1 (64..127):  Gram duty (Mr[32])
// All 4 waves replicate stack state (lane l=tid&63: k=l>>5, m=l&31).
__global__ __attribute__((amdgpu_flat_work_group_size(256, 256), amdgpu_waves_per_eu(1, 1)))
void kC(float* __restrict__ ws, const float* __restrict__ sharp) {
    __shared__ float pkL[64];
    __shared__ float nndL[144];
    __shared__ float nnd2L[64];
    __shared__ float iqL[2];
    const int b = blockIdx.x, tid = threadIdx.x;
    const int wid = tid >> 6, l = tid & 63;
    const int k = l >> 5, m = l & 31;
    const int isRow = (tid < 144);
    const int r2 = 144 + l;            // wave3's calc row

    const float* GI = ws + OFF_GI;
    // per-role register tables
    float G1[64], G2[64];
    float4 Mr[8];
    float A1r = 0.f, A2r = 0.f, B1r = 0.f, B2r = 0.f;
    float A1d = 0.f, A2d = 0.f, B1d = 0.f, B2d = 0.f;
    if (isRow) {
#pragma unroll
        for (int i = 0; i < 32; ++i) {
            G1[i]      = GI[i * 208 + tid];
            G1[32 + i] = GI[(32 + i) * 208 + tid];
        }
        A1r = ws[OFF_A + tid * 3 + 1];  A2r = ws[OFF_A + tid * 3 + 2];
        B1r = ws[OFF_Bc + tid * 3 + 1]; B2r = ws[OFF_Bc + tid * 3 + 2];
    }
    if (wid == 3) {
#pragma unroll
        for (int i = 0; i < 32; ++i) {
            G2[i]      = GI[i * 208 + r2];
            G2[32 + i] = GI[(32 + i) * 208 + r2];
        }
        A1d = ws[OFF_A + r2 * 3 + 1];  A2d = ws[OFF_A + r2 * 3 + 2];
        B1d = ws[OFF_Bc + r2 * 3 + 1]; B2d = ws[OFF_Bc + r2 * 3 + 2];
    }
    if (wid == 1) {
#pragma unroll
        for (int q = 0; q < 8; ++q) Mr[q] = *(const float4*)(ws + OFF_M + m * 32 + q * 4);
    }
    const float sh = sharp[k];

    // replicated stack state
    float st[4], p[4];
#pragma unroll
    for (int d = 0; d < 4; ++d) {
        st[d] = (d == 1) ? ((m == 1) ? 1.f : 0.f) : ((m == 0) ? ZOFF : 0.f);
        p[d] = (d == 1) ? 1.f : 0.f;
    }
    float pk = st[0] * p[0] + st[1] * p[1] + st[2] * p[2] + st[3] * p[3];

    const float* i0base = ws + OFF_I0 + (size_t)b * SS * 208;
    float i0r = isRow ? i0base[tid] : 0.f;
    float i0d = (wid == 3) ? i0base[r2] : 0.f;

    // pre-loop: publish pk, Gram(pk) -> iq
    if (wid == 0) pkL[l] = pk;
    __syncthreads();
    if (wid == 1) {
        const float* ph = pkL + 32 * k;
        float Mv = 0.f;
#pragma unroll
        for (int q = 0; q < 8; ++q) {
            float4 mr = Mr[q];
            float4 a = *(const float4*)(ph + 4 * q);
            Mv += mr.x * a.x + mr.y * a.y + mr.z * a.z + mr.w * a.w;
        }
        float part = pk * Mv;
        part += __shfl_xor(part, 1);  part += __shfl_xor(part, 2);
        part += __shfl_xor(part, 4);  part += __shfl_xor(part, 8);
        part += __shfl_xor(part, 16);
        if ((tid & 31) == 0) iqL[k] = 1.f / fmaxf(sqrtf(part), 1e-8f);
    }
    __syncthreads();
    float iq0 = iqL[0], iq1 = iqL[1];

    for (int t = 0; t < SS; ++t) {
        const int tn = (t < SS - 1) ? (t + 1) : t;
        // ---- region A: phase-1 NAND rows ----
        float i0n = 0.f;
        if (isRow) {
            i0n = i0base[(size_t)tn * 208 + tid];
            float d1 = 0.f, d2 = 0.f;
#pragma unroll
            for (int q = 0; q < 8; ++q) {
                float4 a = *(const float4*)(pkL + 4 * q);
                float4 c = *(const float4*)(pkL + 32 + 4 * q);
                d1 += a.x * G1[4*q] + a.y * G1[4*q+1] + a.z * G1[4*q+2] + a.w * G1[4*q+3];
                d2 += c.x * G1[32+4*q] + c.y * G1[33+4*q] + c.z * G1[34+4*q] + c.w * G1[35+4*q];
            }
            nndL[tid] = i0r * (A1r * fabsf(d1) * iq0 + B1r) * (A2r * fabsf(d2) * iq1 + B2r);
        }
        __syncthreads();   // B1: nndL visible

        // ---- region B: gates + push_val + state update (replicated in all waves) ----
        float4 gp4 = *(const float4*)(nndL + 4 * k);
        float4 gq4 = *(const float4*)(nndL + 8 + 4 * k);
        float prp0 = 1.f / (1.f + __expf((fmaxf(gp4.z, gp4.w) - fmaxf(gp4.x, gp4.y)) * sh));
        float prq0 = 1.f / (1.f + __expf((fmaxf(gq4.z, gq4.w) - fmaxf(gq4.x, gq4.y)) * sh));
        float prp1 = 1.f - prp0, prq1 = 1.f - prq0;
        float prx = 0.f, pry = 0.f;
        if (m >= 2) {
            float2 pr2 = *(const float2*)(nndL + 16 + 64 * k + 2 * m - 4);
            prx = pr2.x; pry = pr2.y;
        }
        float4 t30 = *(const float4*)(nndL + 16 + 64 * k + 60);
        float pkOther = __shfl_xor(pk, 32);
        float pk0m = k ? pkOther : pk;
        float pk1m = k ? pk : pkOther;
        float pvc = prx + pry + (t30.x + t30.y) * pk0m + (t30.z + t30.w) * pk1m;

        float zc = (m == 0) ? ZOFF : 0.f;
        float s1[4], p1[4];
#pragma unroll
        for (int d = 0; d < 4; ++d) {
            float ps = st[d] * (1.f - p[d]) + zc * p[d];
            s1[d] = ps * prp0 + st[d] * prp1;
            p1[d] = p[(d + 1) & 3] * prp0 + p[d] * prp1;
        }
#pragma unroll
        for (int d = 0; d < 4; ++d) {
            float pu = p1[(d + 3) & 3];
            float su = s1[d] * (1.f - pu) + pvc * pu;
            st[d] = su * prq0 + s1[d] * prq1;
            p[d] = pu * prq0 + p1[d] * prq1;
        }
        float pkp = st[0] * p[0] + st[1] * p[1] + st[2] * p[2] + st[3] * p[3];
        if (wid == 0) pkL[l] = pkp;
        __syncthreads();   // B2: pkL' visible

        // ---- region C: calc dots (wave3) + Gram(pk') (wave1) ----
        float dd1 = 0.f, dd2 = 0.f, i0dn = 0.f;
        if (wid == 3) {
            i0dn = i0base[(size_t)tn * 208 + r2];
#pragma unroll
            for (int q = 0; q < 8; ++q) {
                float4 a = *(const float4*)(pkL + 4 * q);
                float4 c = *(const float4*)(pkL + 32 + 4 * q);
                dd1 += a.x * G2[4*q] + a.y * G2[4*q+1] + a.z * G2[4*q+2] + a.w * G2[4*q+3];
                dd2 += c.x * G2[32+4*q] + c.y * G2[33+4*q] + c.z * G2[34+4*q] + c.w * G2[35+4*q];
            }
        } else if (wid == 1) {
            const float* ph = pkL + 32 * k;
            float Mv = 0.f;
#pragma unroll
            for (int q = 0; q < 8; ++q) {
                float4 mr = Mr[q];
                float4 a = *(const float4*)(ph + 4 * q);
                Mv += mr.x * a.x + mr.y * a.y + mr.z * a.z + mr.w * a.w;
            }
            float part = pkp * Mv;
            part += __shfl_xor(part, 1);  part += __shfl_xor(part, 2);
            part += __shfl_xor(part, 4);  part += __shfl_xor(part, 8);
            part += __shfl_xor(part, 16);
            if ((tid & 31) == 0) iqL[k] = 1.f / fmaxf(sqrtf(part), 1e-8f);
        }
        __syncthreads();   // B3: iqL' visible

        // ---- region D: calc nnd (wave3); all refresh iq regs ----
        iq0 = iqL[0]; iq1 = iqL[1];
        if (wid == 3) {
            nnd2L[l] = i0d * (A1d * fabsf(dd1) * iq0 + B1d) * (A2d * fabsf(dd2) * iq1 + B2d);
            i0d = i0dn;
        }
        __syncthreads();   // B4: nnd2L visible

        // ---- region E: output coords (wave0 lanes < 32) ----
        float pkpOther = __shfl_xor(pkp, 32);
        if (tid < 32) {
            float cx = 0.f, cy = 0.f;
            if (m >= 2) {
                float2 c2 = *(const float2*)(nnd2L + 2 * m - 4);
                cx = c2.x; cy = c2.y;
            }
            float4 c30 = *(const float4*)(nnd2L + 60);
            float oc = cx + cy + (c30.x + c30.y) * pkp + (c30.z + c30.w) * pkpOther;
            ws[OFF_OC + ((size_t)b * SS + t) * 32 + m] = oc;
        }
        pk = pkp;
        i0r = i0n;
    }
}

// ---------------- kernel D: expand coords -> 512-dim output (barrier-free) ----------------
__global__ __launch_bounds__(256) void kD(const float* __restrict__ ws, const float* __restrict__ syms,
                                          const float* __restrict__ siv, float* __restrict__ out) {
    int t = threadIdx.x;
    int rg = t >> 6;
    int vc = (t & 63) * 8;
    size_t r0 = (size_t)blockIdx.x * 16 + rg * 4;
    const float* oc = ws + OFF_OC;
    float acc[4][8];
    float4 sv0 = *(const float4*)(siv + vc);
    float4 sv1 = *(const float4*)(siv + vc + 4);
#pragma unroll
    for (int rr = 0; rr < 4; ++rr) {
        float c0 = oc[(r0 + rr) * 32 + 0];
        float c1 = oc[(r0 + rr) * 32 + 1];
        acc[rr][0] = c0 + c1 * sv0.x; acc[rr][1] = c0 + c1 * sv0.y;
        acc[rr][2] = c0 + c1 * sv0.z; acc[rr][3] = c0 + c1 * sv0.w;
        acc[rr][4] = c0 + c1 * sv1.x; acc[rr][5] = c0 + c1 * sv1.y;
        acc[rr][6] = c0 + c1 * sv1.z; acc[rr][7] = c0 + c1 * sv1.w;
    }
    for (int mm = 0; mm < 30; ++mm) {
        float4 b0 = *(const float4*)(syms + mm * 512 + vc);
        float4 b1 = *(const float4*)(syms + mm * 512 + vc + 4);
#pragma unroll
        for (int rr = 0; rr < 4; ++rr) {
            float c = oc[(r0 + rr) * 32 + 2 + mm];
            acc[rr][0] += c * b0.x; acc[rr][1] += c * b0.y;
            acc[rr][2] += c * b0.z; acc[rr][3] += c * b0.w;
            acc[rr][4] += c * b1.x; acc[rr][5] += c * b1.y;
            acc[rr][6] += c * b1.z; acc[rr][7] += c * b1.w;
        }
    }
#pragma unroll
    for (int rr = 0; rr < 4; ++rr) {
        float* o = out + (r0 + rr) * 512 + vc;
        *(float4*)o       = make_float4(acc[rr][0], acc[rr][1], acc[rr][2], acc[rr][3]);
        *(float4*)(o + 4) = make_float4(acc[rr][4], acc[rr][5], acc[rr][6], acc[rr][7]);
    }
}

extern "C" void kernel_launch(void* const* d_in, const int* in_sizes, int n_in,
                              void* d_out, int out_size, void* d_ws, size_t ws_size,
                              hipStream_t stream) {
    const float* x    = (const float*)d_in[0];
    const float* syms = (const float*)d_in[1];
    const float* siv  = (const float*)d_in[2];
    const float* shp  = (const float*)d_in[3];
    const float* pw   = (const float*)d_in[4];
    const float* pn   = (const float*)d_in[5];
    const float* pow_ = (const float*)d_in[6];
    const float* pon  = (const float*)d_in[7];
    const float* pfw  = (const float*)d_in[8];
    const float* pfn  = (const float*)d_in[9];
    const float* cw   = (const float*)d_in[10];
    const float* cn   = (const float*)d_in[11];
    float* ws  = (float*)d_ws;
    float* out = (float*)d_out;

    hipLaunchKernelGGL(kB, dim3(82),   dim3(256), 0, stream,
                       syms, siv, pw, pn, pow_, pon, pfw, pfn, cw, cn, ws);
    hipLaunchKernelGGL(kA, dim3(512),  dim3(256), 0, stream, x, ws);
    hipLaunchKernelGGL(kC, dim3(256),  dim3(256), 0, stream, ws, shp);
    hipLaunchKernelGGL(kD, dim3(2048), dim3(256), 0, stream, ws, syms, siv, out);
}